// Round 1
// baseline (9413.625 us; speedup 1.0000x reference)
//
#include <hip/hip_runtime.h>

#define N_NODES 50000
#define W_IN    256
#define W_OUT   256
#define HEADS   8
#define D_HEAD  32
#define NUM_T   3
#define N_EDGES 800000
#define NEG_SLOPE 0.2f

// ---------------------------------------------------------------------------
// GEMM: H = x @ W   (x: [N_NODES, 256] row-major, W: [256, 256] row-major)
// 64x64 tile, BK=16, 256 threads, 4x4 microtile per thread.
// ---------------------------------------------------------------------------
__global__ __launch_bounds__(256) void gemm_h(const float* __restrict__ x,
                                              const float* __restrict__ W,
                                              float* __restrict__ H) {
    __shared__ float As[16][64];  // [k][m]
    __shared__ float Bs[16][64];  // [k][n]

    const int tid = threadIdx.x;
    const int tx = tid & 15;      // 0..15 -> 4 output cols each
    const int ty = tid >> 4;      // 0..15 -> 4 output rows each
    const int m0 = blockIdx.x * 64;
    const int n0 = blockIdx.y * 64;

    // A loader: row = tid>>2 (0..63), k4 = (tid&3)*4
    const int arow = tid >> 2;
    const int ak   = (tid & 3) * 4;
    // B loader: k = tid>>4 (0..15), n4 = (tid&15)*4
    const int bk = tid >> 4;
    const int bn = (tid & 15) * 4;

    float acc[4][4] = {};

    for (int k0 = 0; k0 < W_IN; k0 += 16) {
        float4 av = make_float4(0.f, 0.f, 0.f, 0.f);
        const int gm = m0 + arow;
        if (gm < N_NODES)
            av = *(const float4*)(x + (size_t)gm * W_IN + k0 + ak);
        As[ak + 0][arow] = av.x;
        As[ak + 1][arow] = av.y;
        As[ak + 2][arow] = av.z;
        As[ak + 3][arow] = av.w;

        const float4 bv = *(const float4*)(W + (size_t)(k0 + bk) * W_OUT + n0 + bn);
        *(float4*)&Bs[bk][bn] = bv;

        __syncthreads();

#pragma unroll
        for (int k = 0; k < 16; ++k) {
            float a[4], b[4];
#pragma unroll
            for (int i = 0; i < 4; ++i) a[i] = As[k][ty * 4 + i];
#pragma unroll
            for (int j = 0; j < 4; ++j) b[j] = Bs[k][tx * 4 + j];
#pragma unroll
            for (int i = 0; i < 4; ++i)
#pragma unroll
                for (int j = 0; j < 4; ++j) acc[i][j] += a[i] * b[j];
        }
        __syncthreads();
    }

#pragma unroll
    for (int i = 0; i < 4; ++i) {
        const int gm = m0 + ty * 4 + i;
        if (gm < N_NODES) {
            float4 v = make_float4(acc[i][0], acc[i][1], acc[i][2], acc[i][3]);
            *(float4*)(H + (size_t)gm * W_OUT + n0 + tx * 4) = v;
        }
    }
}

// ---------------------------------------------------------------------------
// Per-node attention scores: el[n][h] = dot(h[n][h*32:(h+1)*32], a_l[h]),
// same for er. One wave per node; lane l covers dims 4l..4l+3 (head = l>>3).
// ---------------------------------------------------------------------------
__global__ __launch_bounds__(256) void node_scores(const float* __restrict__ H,
                                                   const float* __restrict__ al,
                                                   const float* __restrict__ ar,
                                                   float* __restrict__ el,
                                                   float* __restrict__ er) {
    const int gw = (blockIdx.x * blockDim.x + threadIdx.x) >> 6;
    const int lane = threadIdx.x & 63;
    if (gw >= N_NODES) return;

    const float4 hv  = *(const float4*)(H + (size_t)gw * W_OUT + lane * 4);
    const float4 alv = *(const float4*)(al + lane * 4);
    const float4 arv = *(const float4*)(ar + lane * 4);

    float pl = hv.x * alv.x + hv.y * alv.y + hv.z * alv.z + hv.w * alv.w;
    float pr = hv.x * arv.x + hv.y * arv.y + hv.z * arv.z + hv.w * arv.w;

    // reduce within 8-lane groups (one head each)
#pragma unroll
    for (int off = 1; off < 8; off <<= 1) {
        pl += __shfl_xor(pl, off);
        pr += __shfl_xor(pr, off);
    }
    if ((lane & 7) == 0) {
        const int hh = lane >> 3;
        el[(size_t)gw * HEADS + hh] = pl;
        er[(size_t)gw * HEADS + hh] = pr;
    }
}

// ---------------------------------------------------------------------------
// Softmax denominators: s[dst][h] += exp(leaky_relu(el[src][h] + er[dst][h]))
// (segment-max skipped: cancels exactly up to the +1e-9; scores bounded)
// ---------------------------------------------------------------------------
__global__ __launch_bounds__(256) void edge_sums(const int* __restrict__ adj,
                                                 const float* __restrict__ el,
                                                 const float* __restrict__ er,
                                                 float* __restrict__ s) {
    const int e = blockIdx.x * blockDim.x + threadIdx.x;
    if (e >= N_EDGES) return;
    const int src = adj[e];
    const int dst = adj[N_EDGES + e];
    const float* elp = el + (size_t)src * HEADS;
    const float* erp = er + (size_t)dst * HEADS;
    float* sp = s + (size_t)dst * HEADS;
#pragma unroll
    for (int hh = 0; hh < HEADS; ++hh) {
        float v = elp[hh] + erp[hh];
        v = (v > 0.f) ? v : NEG_SLOPE * v;
        atomicAdd(&sp[hh], __expf(v));
    }
}

// ---------------------------------------------------------------------------
// Scatter: out[dst] += alpha * h[src]. One wave per edge; lane l covers
// dims 4l..4l+3, head = l>>3, alpha recomputed per lane.
// ---------------------------------------------------------------------------
__global__ __launch_bounds__(256) void edge_scatter(const int* __restrict__ adj,
                                                    const float* __restrict__ el,
                                                    const float* __restrict__ er,
                                                    const float* __restrict__ s,
                                                    const float* __restrict__ H,
                                                    float* __restrict__ ot) {
    const int gw = (blockIdx.x * blockDim.x + threadIdx.x) >> 6;
    const int lane = threadIdx.x & 63;
    if (gw >= N_EDGES) return;

    const int src = adj[gw];
    const int dst = adj[N_EDGES + gw];
    const int hh = lane >> 3;

    const float elv = el[(size_t)src * HEADS + hh];
    const float erv = er[(size_t)dst * HEADS + hh];
    const float sv  = s[(size_t)dst * HEADS + hh];
    float v = elv + erv;
    v = (v > 0.f) ? v : NEG_SLOPE * v;
    const float alpha = __expf(v) / (sv + 1e-9f);

    const float4 hv = *(const float4*)(H + (size_t)src * W_OUT + lane * 4);
    float* op = ot + (size_t)dst * W_OUT + lane * 4;
    atomicAdd(op + 0, alpha * hv.x);
    atomicAdd(op + 1, alpha * hv.y);
    atomicAdd(op + 2, alpha * hv.z);
    atomicAdd(op + 3, alpha * hv.w);
}

// ---------------------------------------------------------------------------
// Semantic attention: att[t] = dot(stacked[n][t], att_w) + att_b  (no softmax),
// out[n] = sum_t att[t] * stacked[n][t].  One wave per node. ot2 == out (in
// place; each lane reads its own float4 before writing it).
// ---------------------------------------------------------------------------
__global__ __launch_bounds__(256) void combine(const float* __restrict__ ot0,
                                               const float* __restrict__ ot1,
                                               const float* __restrict__ ot2,
                                               const float* __restrict__ bias,
                                               const float* __restrict__ att_w,
                                               const float* __restrict__ att_b,
                                               float* __restrict__ out) {
    const int gw = (blockIdx.x * blockDim.x + threadIdx.x) >> 6;
    const int lane = threadIdx.x & 63;
    if (gw >= N_NODES) return;

    const float4 aw = *(const float4*)(att_w + lane * 4);
    const size_t base = (size_t)gw * W_OUT + lane * 4;

    float4 v[NUM_T];
    float p[NUM_T];
    const float* ots[NUM_T] = {ot0, ot1, ot2};
#pragma unroll
    for (int t = 0; t < NUM_T; ++t) {
        float4 hv = *(const float4*)(ots[t] + base);
        const float4 bv = *(const float4*)(bias + t * W_OUT + lane * 4);
        hv.x += bv.x; hv.y += bv.y; hv.z += bv.z; hv.w += bv.w;
        v[t] = hv;
        p[t] = hv.x * aw.x + hv.y * aw.y + hv.z * aw.z + hv.w * aw.w;
    }
#pragma unroll
    for (int off = 1; off < 64; off <<= 1) {
        p[0] += __shfl_xor(p[0], off);
        p[1] += __shfl_xor(p[1], off);
        p[2] += __shfl_xor(p[2], off);
    }
    const float ab = att_b[0];
    const float a0 = p[0] + ab, a1 = p[1] + ab, a2 = p[2] + ab;
    float4 o;
    o.x = a0 * v[0].x + a1 * v[1].x + a2 * v[2].x;
    o.y = a0 * v[0].y + a1 * v[1].y + a2 * v[2].y;
    o.z = a0 * v[0].z + a1 * v[1].z + a2 * v[2].z;
    o.w = a0 * v[0].w + a1 * v[1].w + a2 * v[2].w;
    *(float4*)(out + base) = o;
}

// ---------------------------------------------------------------------------
extern "C" void kernel_launch(void* const* d_in, const int* in_sizes, int n_in,
                              void* d_out, int out_size, void* d_ws, size_t ws_size,
                              hipStream_t stream) {
    const float* x     = (const float*)d_in[0];
    const int*   adj   = (const int*)d_in[1];   // [3][2][N_EDGES]
    const float* Ws    = (const float*)d_in[2]; // [3][256][256]
    const float* a_l   = (const float*)d_in[3]; // [3][8][32]
    const float* a_r   = (const float*)d_in[4];
    const float* bias  = (const float*)d_in[5]; // [3][256]
    const float* att_w = (const float*)d_in[6]; // [256]
    const float* att_b = (const float*)d_in[7]; // [1]
    float* out = (float*)d_out;

    // Workspace layout (floats). Types processed sequentially so h is reused;
    // d_out doubles as the t=2 accumulator. Total = 158.4 MB.
    float* ws = (float*)d_ws;
    float* h   = ws;                          // 12.8M floats
    float* ot0 = h + (size_t)N_NODES * W_OUT; // 12.8M
    float* ot1 = ot0 + (size_t)N_NODES * W_OUT;
    float* el  = ot1 + (size_t)N_NODES * W_OUT; // 400k
    float* er  = el + (size_t)N_NODES * HEADS;
    float* s   = er + (size_t)N_NODES * HEADS;

    // Zero accumulators (harness poisons d_out/d_ws with 0xAA each call)
    hipMemsetAsync(out, 0, (size_t)N_NODES * W_OUT * sizeof(float), stream);
    hipMemsetAsync(ot0, 0, (size_t)2 * N_NODES * W_OUT * sizeof(float), stream);

    float* ot[NUM_T] = {ot0, ot1, out};

    const dim3 gemm_grid((N_NODES + 63) / 64, W_OUT / 64);
    const int node_waves_blocks = (N_NODES + 3) / 4;   // 4 waves/block
    const int edge_blocks = (N_EDGES + 255) / 256;
    const int edge_wave_blocks = (N_EDGES + 3) / 4;    // 1 wave/edge

    for (int t = 0; t < NUM_T; ++t) {
        const int*   adjt = adj + (size_t)t * 2 * N_EDGES;
        const float* Wt   = Ws + (size_t)t * W_IN * W_OUT;

        hipMemsetAsync(s, 0, (size_t)N_NODES * HEADS * sizeof(float), stream);

        gemm_h<<<gemm_grid, 256, 0, stream>>>(x, Wt, h);
        node_scores<<<node_waves_blocks, 256, 0, stream>>>(
            h, a_l + t * HEADS * D_HEAD, a_r + t * HEADS * D_HEAD, el, er);
        edge_sums<<<edge_blocks, 256, 0, stream>>>(adjt, el, er, s);
        edge_scatter<<<edge_wave_blocks, 256, 0, stream>>>(adjt, el, er, s, h, ot[t]);
    }

    combine<<<node_waves_blocks, 256, 0, stream>>>(ot0, ot1, out, bias, att_w,
                                                   att_b, out);
}

// Round 2
// 1379.367 us; speedup vs baseline: 6.8246x; 6.8246x over previous
//
#include <hip/hip_runtime.h>

#define N_NODES 50000
#define W_IN    256
#define W_OUT   256
#define HEADS   8
#define D_HEAD  32
#define NUM_T   3
#define N_EDGES 800000
#define NEG_SLOPE 0.2f
#define SCAN_T  1024

// ---------------------------------------------------------------------------
// GEMM: H = x @ W   (x: [N_NODES, 256] row-major, W: [256, 256] row-major)
// 64x64 tile, BK=16, 256 threads, 4x4 microtile per thread.
// ---------------------------------------------------------------------------
__global__ __launch_bounds__(256) void gemm_h(const float* __restrict__ x,
                                              const float* __restrict__ W,
                                              float* __restrict__ H) {
    __shared__ float As[16][64];  // [k][m]
    __shared__ float Bs[16][64];  // [k][n]

    const int tid = threadIdx.x;
    const int tx = tid & 15;
    const int ty = tid >> 4;
    const int m0 = blockIdx.x * 64;
    const int n0 = blockIdx.y * 64;

    const int arow = tid >> 2;
    const int ak   = (tid & 3) * 4;
    const int bk = tid >> 4;
    const int bn = (tid & 15) * 4;

    float acc[4][4] = {};

    for (int k0 = 0; k0 < W_IN; k0 += 16) {
        float4 av = make_float4(0.f, 0.f, 0.f, 0.f);
        const int gm = m0 + arow;
        if (gm < N_NODES)
            av = *(const float4*)(x + (size_t)gm * W_IN + k0 + ak);
        As[ak + 0][arow] = av.x;
        As[ak + 1][arow] = av.y;
        As[ak + 2][arow] = av.z;
        As[ak + 3][arow] = av.w;

        const float4 bv = *(const float4*)(W + (size_t)(k0 + bk) * W_OUT + n0 + bn);
        *(float4*)&Bs[bk][bn] = bv;

        __syncthreads();

#pragma unroll
        for (int k = 0; k < 16; ++k) {
            float a[4], b[4];
#pragma unroll
            for (int i = 0; i < 4; ++i) a[i] = As[k][ty * 4 + i];
#pragma unroll
            for (int j = 0; j < 4; ++j) b[j] = Bs[k][tx * 4 + j];
#pragma unroll
            for (int i = 0; i < 4; ++i)
#pragma unroll
                for (int j = 0; j < 4; ++j) acc[i][j] += a[i] * b[j];
        }
        __syncthreads();
    }

#pragma unroll
    for (int i = 0; i < 4; ++i) {
        const int gm = m0 + ty * 4 + i;
        if (gm < N_NODES) {
            float4 v = make_float4(acc[i][0], acc[i][1], acc[i][2], acc[i][3]);
            *(float4*)(H + (size_t)gm * W_OUT + n0 + tx * 4) = v;
        }
    }
}

// ---------------------------------------------------------------------------
// Per-node attention scores. One wave per node; lane l covers dims 4l..4l+3
// (head = l>>3).
// ---------------------------------------------------------------------------
__global__ __launch_bounds__(256) void node_scores(const float* __restrict__ H,
                                                   const float* __restrict__ al,
                                                   const float* __restrict__ ar,
                                                   float* __restrict__ el,
                                                   float* __restrict__ er) {
    const int gw = (blockIdx.x * blockDim.x + threadIdx.x) >> 6;
    const int lane = threadIdx.x & 63;
    if (gw >= N_NODES) return;

    const float4 hv  = *(const float4*)(H + (size_t)gw * W_OUT + lane * 4);
    const float4 alv = *(const float4*)(al + lane * 4);
    const float4 arv = *(const float4*)(ar + lane * 4);

    float pl = hv.x * alv.x + hv.y * alv.y + hv.z * alv.z + hv.w * alv.w;
    float pr = hv.x * arv.x + hv.y * arv.y + hv.z * arv.z + hv.w * arv.w;

#pragma unroll
    for (int off = 1; off < 8; off <<= 1) {
        pl += __shfl_xor(pl, off);
        pr += __shfl_xor(pr, off);
    }
    if ((lane & 7) == 0) {
        const int hh = lane >> 3;
        el[(size_t)gw * HEADS + hh] = pl;
        er[(size_t)gw * HEADS + hh] = pr;
    }
}

// ---------------------------------------------------------------------------
// CSR build step 1: histogram of dst.
// ---------------------------------------------------------------------------
__global__ __launch_bounds__(256) void count_edges(const int* __restrict__ adj_dst,
                                                   int* __restrict__ cnt) {
    const int e = blockIdx.x * blockDim.x + threadIdx.x;
    if (e < N_EDGES) atomicAdd(&cnt[adj_dst[e]], 1);
}

// ---------------------------------------------------------------------------
// CSR build step 2: exclusive scan of 50000 counts. Single block, 1024 thr.
// Each thread scans a contiguous chunk; block-level Hillis-Steele in LDS.
// ---------------------------------------------------------------------------
__global__ __launch_bounds__(SCAN_T) void scan_rows(const int* __restrict__ cnt,
                                                    int* __restrict__ row_ptr,
                                                    int* __restrict__ row_cur) {
    __shared__ int sums[SCAN_T];
    const int t = threadIdx.x;
    const int chunk = (N_NODES + SCAN_T - 1) / SCAN_T;  // 49
    const int beg = t * chunk;
    int end = beg + chunk;
    if (end > N_NODES) end = N_NODES;

    int local = 0;
    for (int i = beg; i < end; ++i) local += cnt[i];
    sums[t] = local;
    __syncthreads();

    for (int off = 1; off < SCAN_T; off <<= 1) {
        int other = 0;
        if (t >= off) other = sums[t - off];
        __syncthreads();
        sums[t] += other;
        __syncthreads();
    }

    int run = sums[t] - local;  // exclusive prefix of this chunk
    for (int i = beg; i < end; ++i) {
        row_ptr[i] = run;
        row_cur[i] = run;
        run += cnt[i];
    }
    if (t == SCAN_T - 1) row_ptr[N_NODES] = run;
}

// ---------------------------------------------------------------------------
// CSR build step 3: bucket src ids by dst.
// ---------------------------------------------------------------------------
__global__ __launch_bounds__(256) void bucket_edges(const int* __restrict__ adj,
                                                    int* __restrict__ row_cur,
                                                    int* __restrict__ csr_src) {
    const int e = blockIdx.x * blockDim.x + threadIdx.x;
    if (e >= N_EDGES) return;
    const int src = adj[e];
    const int dst = adj[N_EDGES + e];
    const int pos = atomicAdd(&row_cur[dst], 1);
    csr_src[pos] = src;
}

// ---------------------------------------------------------------------------
// Fused denominator + weighted gather. One wave per dst node. Lane l covers
// dims 4l..4l+3 (head hh = l>>3). For each incoming edge:
//   w = exp(leaky_relu(el[src][hh] + er[dst][hh]))
//   acc += w * h[src];  s += w
// out[dst] = acc / (s + 1e-9). No atomics; each output row written once.
// Lanes cooperatively load up to 64 src ids (coalesced), then broadcast via
// __shfl so the per-edge loop has no serial pointer chase.
// ---------------------------------------------------------------------------
__global__ __launch_bounds__(256) void gat_gather(const int* __restrict__ csr_src,
                                                  const int* __restrict__ row_ptr,
                                                  const float* __restrict__ el,
                                                  const float* __restrict__ er,
                                                  const float* __restrict__ H,
                                                  float* __restrict__ ot) {
    const int node = (blockIdx.x * blockDim.x + threadIdx.x) >> 6;
    const int lane = threadIdx.x & 63;
    if (node >= N_NODES) return;
    const int hh = lane >> 3;

    const int beg = row_ptr[node];
    const int end = row_ptr[node + 1];
    const float erv = er[(size_t)node * HEADS + hh];

    float4 acc = make_float4(0.f, 0.f, 0.f, 0.f);
    float ssum = 0.f;

    for (int j0 = beg; j0 < end; j0 += 64) {
        int nsrc = end - j0;
        if (nsrc > 64) nsrc = 64;
        int mysrc = 0;
        if (j0 + lane < end) mysrc = csr_src[j0 + lane];

        for (int j = 0; j < nsrc; ++j) {
            const int src = __shfl(mysrc, j);
            float v = el[(size_t)src * HEADS + hh] + erv;
            v = (v > 0.f) ? v : NEG_SLOPE * v;
            const float w = __expf(v);
            const float4 hv = *(const float4*)(H + (size_t)src * W_OUT + lane * 4);
            acc.x += w * hv.x;
            acc.y += w * hv.y;
            acc.z += w * hv.z;
            acc.w += w * hv.w;
            ssum += w;
        }
    }

    const float inv = 1.f / (ssum + 1e-9f);  // deg==0 -> acc==0 -> writes 0
    float4 o = make_float4(acc.x * inv, acc.y * inv, acc.z * inv, acc.w * inv);
    *(float4*)(ot + (size_t)node * W_OUT + lane * 4) = o;
}

// ---------------------------------------------------------------------------
// Semantic attention combine (unchanged; ot2 == out, in place is safe).
// ---------------------------------------------------------------------------
__global__ __launch_bounds__(256) void combine(const float* __restrict__ ot0,
                                               const float* __restrict__ ot1,
                                               const float* __restrict__ ot2,
                                               const float* __restrict__ bias,
                                               const float* __restrict__ att_w,
                                               const float* __restrict__ att_b,
                                               float* __restrict__ out) {
    const int gw = (blockIdx.x * blockDim.x + threadIdx.x) >> 6;
    const int lane = threadIdx.x & 63;
    if (gw >= N_NODES) return;

    const float4 aw = *(const float4*)(att_w + lane * 4);
    const size_t base = (size_t)gw * W_OUT + lane * 4;

    float4 v[NUM_T];
    float p[NUM_T];
    const float* ots[NUM_T] = {ot0, ot1, ot2};
#pragma unroll
    for (int t = 0; t < NUM_T; ++t) {
        float4 hv = *(const float4*)(ots[t] + base);
        const float4 bv = *(const float4*)(bias + t * W_OUT + lane * 4);
        hv.x += bv.x; hv.y += bv.y; hv.z += bv.z; hv.w += bv.w;
        v[t] = hv;
        p[t] = hv.x * aw.x + hv.y * aw.y + hv.z * aw.z + hv.w * aw.w;
    }
#pragma unroll
    for (int off = 1; off < 64; off <<= 1) {
        p[0] += __shfl_xor(p[0], off);
        p[1] += __shfl_xor(p[1], off);
        p[2] += __shfl_xor(p[2], off);
    }
    const float ab = att_b[0];
    const float a0 = p[0] + ab, a1 = p[1] + ab, a2 = p[2] + ab;
    float4 o;
    o.x = a0 * v[0].x + a1 * v[1].x + a2 * v[2].x;
    o.y = a0 * v[0].y + a1 * v[1].y + a2 * v[2].y;
    o.z = a0 * v[0].z + a1 * v[1].z + a2 * v[2].z;
    o.w = a0 * v[0].w + a1 * v[1].w + a2 * v[2].w;
    *(float4*)(out + base) = o;
}

// ---------------------------------------------------------------------------
extern "C" void kernel_launch(void* const* d_in, const int* in_sizes, int n_in,
                              void* d_out, int out_size, void* d_ws, size_t ws_size,
                              hipStream_t stream) {
    const float* x     = (const float*)d_in[0];
    const int*   adj   = (const int*)d_in[1];   // [3][2][N_EDGES]
    const float* Ws    = (const float*)d_in[2]; // [3][256][256]
    const float* a_l   = (const float*)d_in[3]; // [3][8][32]
    const float* a_r   = (const float*)d_in[4];
    const float* bias  = (const float*)d_in[5]; // [3][256]
    const float* att_w = (const float*)d_in[6]; // [256]
    const float* att_b = (const float*)d_in[7]; // [1]
    float* out = (float*)d_out;

    // Workspace layout. Types processed sequentially so h / CSR are reused;
    // d_out doubles as the t=2 accumulator. ~160.6 MB total.
    float* ws = (float*)d_ws;
    float* h   = ws;                            // 12.8M floats
    float* ot0 = h + (size_t)N_NODES * W_OUT;   // 12.8M
    float* ot1 = ot0 + (size_t)N_NODES * W_OUT; // 12.8M
    float* el  = ot1 + (size_t)N_NODES * W_OUT; // 400k
    float* er  = el + (size_t)N_NODES * HEADS;  // 400k
    int* csr_src = (int*)(er + (size_t)N_NODES * HEADS); // 800k ints
    int* row_ptr = csr_src + N_EDGES;           // 50001
    int* row_cnt = row_ptr + (N_NODES + 1);     // 50000
    int* row_cur = row_cnt + N_NODES;           // 50000

    float* ot[NUM_T] = {ot0, ot1, out};

    const dim3 gemm_grid((N_NODES + 63) / 64, W_OUT / 64);
    const int node_wave_blocks = (N_NODES + 3) / 4;  // 4 waves/block
    const int edge_blocks = (N_EDGES + 255) / 256;

    for (int t = 0; t < NUM_T; ++t) {
        const int*   adjt = adj + (size_t)t * 2 * N_EDGES;
        const float* Wt   = Ws + (size_t)t * W_IN * W_OUT;

        hipMemsetAsync(row_cnt, 0, (size_t)N_NODES * sizeof(int), stream);

        gemm_h<<<gemm_grid, 256, 0, stream>>>(x, Wt, h);
        node_scores<<<node_wave_blocks, 256, 0, stream>>>(
            h, a_l + t * HEADS * D_HEAD, a_r + t * HEADS * D_HEAD, el, er);
        count_edges<<<edge_blocks, 256, 0, stream>>>(adjt + N_EDGES, row_cnt);
        scan_rows<<<1, SCAN_T, 0, stream>>>(row_cnt, row_ptr, row_cur);
        bucket_edges<<<edge_blocks, 256, 0, stream>>>(adjt, row_cur, csr_src);
        gat_gather<<<node_wave_blocks, 256, 0, stream>>>(csr_src, row_ptr, el,
                                                         er, h, ot[t]);
    }

    combine<<<node_wave_blocks, 256, 0, stream>>>(ot0, ot1, out, bias, att_w,
                                                  att_b, out);
}

// Round 3
// 841.258 us; speedup vs baseline: 11.1899x; 1.6396x over previous
//
#include <hip/hip_runtime.h>

#define N_NODES 50000
#define W_IN    256
#define W_OUT   256
#define HEADS   8
#define NUM_T   3
#define N_EDGES 800000
#define NEG_SLOPE 0.2f
#define SCAN_T  1024

typedef __attribute__((ext_vector_type(8))) short bf16x8;
typedef __attribute__((ext_vector_type(4))) float f32x4;

__device__ __forceinline__ unsigned short f2b(float f) {
    unsigned u = __float_as_uint(f);
    u = (u + 0x7fffu + ((u >> 16) & 1u)) >> 16;
    return (unsigned short)u;
}
__device__ __forceinline__ float b2f(unsigned short h) {
    return __uint_as_float(((unsigned)h) << 16);
}

// ---------------------------------------------------------------------------
// x fp32 -> bf16 (RNE). Exact grid: 12500*256 threads * 4 elems = 12.8M.
// ---------------------------------------------------------------------------
__global__ __launch_bounds__(256) void convert_x(const float* __restrict__ x,
                                                 unsigned short* __restrict__ xb) {
    const size_t i = ((size_t)blockIdx.x * 256 + threadIdx.x) * 4;
    const float4 v = *(const float4*)(x + i);
    ushort4 o;
    o.x = f2b(v.x); o.y = f2b(v.y); o.z = f2b(v.z); o.w = f2b(v.w);
    *(ushort4*)(xb + i) = o;
}

// ---------------------------------------------------------------------------
// W fp32 [t][k][n] -> bf16 transposed [t][n][k] (so B-tile staging is
// k-contiguous, matching the MFMA B-fragment's 8-contiguous-k layout).
// ---------------------------------------------------------------------------
__global__ __launch_bounds__(256) void convert_W(const float* __restrict__ Wsrc,
                                                 unsigned short* __restrict__ Wt) {
    const int t = blockIdx.y;
    const int gid = blockIdx.x * 256 + threadIdx.x;  // 0..65535
    const int k = gid >> 8, n = gid & 255;
    Wt[(size_t)t * 65536 + (size_t)n * 256 + k] = f2b(Wsrc[(size_t)t * 65536 + gid]);
}

// ---------------------------------------------------------------------------
// GEMM: H = xb @ W  via bf16 MFMA 16x16x32. Tile 64m x 256n, BK=32,
// 256 threads = 4 waves; wave w owns n-slice [w*64, w*64+64) -> 4x4 frags.
// LDS rows padded to 40 bf16 (80 B, 16B-aligned, non-pow2 banks -> <=2-way).
// x rows are read exactly once (full N in one block).
// ---------------------------------------------------------------------------
__global__ __launch_bounds__(256) void gemm_bf16(const unsigned short* __restrict__ xb,
                                                 const unsigned short* __restrict__ Wt,
                                                 unsigned short* __restrict__ H) {
    __shared__ unsigned short As[64 * 40];
    __shared__ unsigned short Bs[256 * 40];

    const int tid = threadIdx.x;
    const int wave = tid >> 6;
    const int lane = tid & 63;
    const int quad = lane >> 4;
    const int l16 = lane & 15;
    const int m0 = blockIdx.x * 64;

    f32x4 acc[4][4] = {};

    const int arow = tid >> 2;          // 0..63
    const int achunk = (tid & 3) * 8;   // bf16 units
    int gm = m0 + arow;
    if (gm > N_NODES - 1) gm = N_NODES - 1;   // clamp tail loads
    const unsigned short* aptr = xb + (size_t)gm * W_IN + achunk;

    for (int k0 = 0; k0 < W_IN; k0 += 32) {
        const uint4 av = *(const uint4*)(aptr + k0);
        *(uint4*)&As[arow * 40 + achunk] = av;
#pragma unroll
        for (int i = 0; i < 4; ++i) {
            const int idx = i * 256 + tid;
            const int brow = idx >> 2;          // 0..255
            const int bch = (idx & 3) * 8;
            const uint4 bv = *(const uint4*)(Wt + (size_t)brow * W_IN + k0 + bch);
            *(uint4*)&Bs[brow * 40 + bch] = bv;
        }
        __syncthreads();

        bf16x8 af[4], bfr[4];
#pragma unroll
        for (int mi = 0; mi < 4; ++mi)
            af[mi] = *(const bf16x8*)&As[(mi * 16 + l16) * 40 + quad * 8];
#pragma unroll
        for (int ni = 0; ni < 4; ++ni)
            bfr[ni] = *(const bf16x8*)&Bs[(wave * 64 + ni * 16 + l16) * 40 + quad * 8];
#pragma unroll
        for (int mi = 0; mi < 4; ++mi)
#pragma unroll
            for (int ni = 0; ni < 4; ++ni)
                acc[mi][ni] = __builtin_amdgcn_mfma_f32_16x16x32_bf16(
                    af[mi], bfr[ni], acc[mi][ni], 0, 0, 0);
        __syncthreads();
    }

    // C/D layout: col = lane&15, row = quad*4 + reg  [m89-verified]
#pragma unroll
    for (int mi = 0; mi < 4; ++mi) {
#pragma unroll
        for (int reg = 0; reg < 4; ++reg) {
            const int gr = m0 + mi * 16 + quad * 4 + reg;
            if (gr < N_NODES) {
#pragma unroll
                for (int ni = 0; ni < 4; ++ni) {
                    const int gc = wave * 64 + ni * 16 + l16;
                    H[(size_t)gr * W_OUT + gc] = f2b(acc[mi][ni][reg]);
                }
            }
        }
    }
}

// ---------------------------------------------------------------------------
// Per-node attention scores from bf16 H. One wave/node; lane l covers dims
// 4l..4l+3 (head = l>>3).
// ---------------------------------------------------------------------------
__global__ __launch_bounds__(256) void node_scores(const unsigned short* __restrict__ H,
                                                   const float* __restrict__ al,
                                                   const float* __restrict__ ar,
                                                   float* __restrict__ el,
                                                   float* __restrict__ er) {
    const int gw = (blockIdx.x * blockDim.x + threadIdx.x) >> 6;
    const int lane = threadIdx.x & 63;
    if (gw >= N_NODES) return;

    const uint2 u = *(const uint2*)(H + (size_t)gw * W_OUT + lane * 4);
    const float h0 = __uint_as_float(u.x << 16);
    const float h1 = __uint_as_float(u.x & 0xffff0000u);
    const float h2 = __uint_as_float(u.y << 16);
    const float h3 = __uint_as_float(u.y & 0xffff0000u);

    const float4 alv = *(const float4*)(al + lane * 4);
    const float4 arv = *(const float4*)(ar + lane * 4);

    float pl = h0 * alv.x + h1 * alv.y + h2 * alv.z + h3 * alv.w;
    float pr = h0 * arv.x + h1 * arv.y + h2 * arv.z + h3 * arv.w;

#pragma unroll
    for (int off = 1; off < 8; off <<= 1) {
        pl += __shfl_xor(pl, off);
        pr += __shfl_xor(pr, off);
    }
    if ((lane & 7) == 0) {
        const int hh = lane >> 3;
        el[(size_t)gw * HEADS + hh] = pl;
        er[(size_t)gw * HEADS + hh] = pr;
    }
}

// ---------------------------------------------------------------------------
// CSR build (all 3 types at once; depends only on adj).
// ---------------------------------------------------------------------------
__global__ __launch_bounds__(256) void count_all(const int* __restrict__ adj,
                                                 int* __restrict__ cnt) {
    const int t = blockIdx.y;
    const int e = blockIdx.x * 256 + threadIdx.x;
    if (e < N_EDGES)
        atomicAdd(&cnt[(size_t)t * N_NODES + adj[(size_t)t * 2 * N_EDGES + N_EDGES + e]], 1);
}

__global__ __launch_bounds__(SCAN_T) void scan_all(const int* __restrict__ cnt_all,
                                                   int* __restrict__ row_ptr_all,
                                                   int* __restrict__ row_cur_all) {
    __shared__ int sums[SCAN_T];
    const int ty = blockIdx.x;  // edge type
    const int* cnt = cnt_all + (size_t)ty * N_NODES;
    int* row_ptr = row_ptr_all + (size_t)ty * (N_NODES + 1);
    int* row_cur = row_cur_all + (size_t)ty * N_NODES;

    const int t = threadIdx.x;
    const int chunk = (N_NODES + SCAN_T - 1) / SCAN_T;  // 49
    const int beg = t * chunk;
    int end = beg + chunk;
    if (end > N_NODES) end = N_NODES;

    int local = 0;
    for (int i = beg; i < end; ++i) local += cnt[i];
    sums[t] = local;
    __syncthreads();

    for (int off = 1; off < SCAN_T; off <<= 1) {
        int other = 0;
        if (t >= off) other = sums[t - off];
        __syncthreads();
        sums[t] += other;
        __syncthreads();
    }

    int run = sums[t] - local;
    for (int i = beg; i < end; ++i) {
        row_ptr[i] = run;
        row_cur[i] = run;
        run += cnt[i];
    }
    if (t == SCAN_T - 1) row_ptr[N_NODES] = run;
}

__global__ __launch_bounds__(256) void bucket_all(const int* __restrict__ adj,
                                                  int* __restrict__ row_cur_all,
                                                  int* __restrict__ csr_all) {
    const int t = blockIdx.y;
    const int e = blockIdx.x * 256 + threadIdx.x;
    if (e >= N_EDGES) return;
    const int src = adj[(size_t)t * 2 * N_EDGES + e];
    const int dst = adj[(size_t)t * 2 * N_EDGES + N_EDGES + e];
    const int pos = atomicAdd(&row_cur_all[(size_t)t * N_NODES + dst], 1);
    csr_all[(size_t)t * N_EDGES + pos] = src;
}

// ---------------------------------------------------------------------------
// Fused denominator + weighted gather, bf16 rows. One wave per dst node.
// ---------------------------------------------------------------------------
__global__ __launch_bounds__(256) void gat_gather(const int* __restrict__ csr_src,
                                                  const int* __restrict__ row_ptr,
                                                  const float* __restrict__ el,
                                                  const float* __restrict__ er,
                                                  const unsigned short* __restrict__ H,
                                                  float* __restrict__ ot) {
    const int node = (blockIdx.x * blockDim.x + threadIdx.x) >> 6;
    const int lane = threadIdx.x & 63;
    if (node >= N_NODES) return;
    const int hh = lane >> 3;

    const int beg = row_ptr[node];
    const int end = row_ptr[node + 1];
    const float erv = er[(size_t)node * HEADS + hh];

    float4 acc = make_float4(0.f, 0.f, 0.f, 0.f);
    float ssum = 0.f;

    for (int j0 = beg; j0 < end; j0 += 64) {
        int nsrc = end - j0;
        if (nsrc > 64) nsrc = 64;
        int mysrc = 0;
        if (j0 + lane < end) mysrc = csr_src[j0 + lane];

        for (int j = 0; j < nsrc; ++j) {
            const int src = __shfl(mysrc, j);
            float v = el[(size_t)src * HEADS + hh] + erv;
            v = (v > 0.f) ? v : NEG_SLOPE * v;
            const float w = __expf(v);
            const uint2 u = *(const uint2*)(H + (size_t)src * W_OUT + lane * 4);
            acc.x += w * __uint_as_float(u.x << 16);
            acc.y += w * __uint_as_float(u.x & 0xffff0000u);
            acc.z += w * __uint_as_float(u.y << 16);
            acc.w += w * __uint_as_float(u.y & 0xffff0000u);
            ssum += w;
        }
    }

    const float inv = 1.f / (ssum + 1e-9f);
    float4 o = make_float4(acc.x * inv, acc.y * inv, acc.z * inv, acc.w * inv);
    *(float4*)(ot + (size_t)node * W_OUT + lane * 4) = o;
}

// ---------------------------------------------------------------------------
// Semantic attention combine (ot2 == out fp32, in place).
// ---------------------------------------------------------------------------
__global__ __launch_bounds__(256) void combine(const float* __restrict__ ot0,
                                               const float* __restrict__ ot1,
                                               const float* __restrict__ ot2,
                                               const float* __restrict__ bias,
                                               const float* __restrict__ att_w,
                                               const float* __restrict__ att_b,
                                               float* __restrict__ out) {
    const int gw = (blockIdx.x * blockDim.x + threadIdx.x) >> 6;
    const int lane = threadIdx.x & 63;
    if (gw >= N_NODES) return;

    const float4 aw = *(const float4*)(att_w + lane * 4);
    const size_t base = (size_t)gw * W_OUT + lane * 4;

    float4 v[NUM_T];
    float p[NUM_T];
    const float* ots[NUM_T] = {ot0, ot1, ot2};
#pragma unroll
    for (int t = 0; t < NUM_T; ++t) {
        float4 hv = *(const float4*)(ots[t] + base);
        const float4 bv = *(const float4*)(bias + t * W_OUT + lane * 4);
        hv.x += bv.x; hv.y += bv.y; hv.z += bv.z; hv.w += bv.w;
        v[t] = hv;
        p[t] = hv.x * aw.x + hv.y * aw.y + hv.z * aw.z + hv.w * aw.w;
    }
#pragma unroll
    for (int off = 1; off < 64; off <<= 1) {
        p[0] += __shfl_xor(p[0], off);
        p[1] += __shfl_xor(p[1], off);
        p[2] += __shfl_xor(p[2], off);
    }
    const float ab = att_b[0];
    const float a0 = p[0] + ab, a1 = p[1] + ab, a2 = p[2] + ab;
    float4 o;
    o.x = a0 * v[0].x + a1 * v[1].x + a2 * v[2].x;
    o.y = a0 * v[0].y + a1 * v[1].y + a2 * v[2].y;
    o.z = a0 * v[0].z + a1 * v[1].z + a2 * v[2].z;
    o.w = a0 * v[0].w + a1 * v[1].w + a2 * v[2].w;
    *(float4*)(out + base) = o;
}

// ---------------------------------------------------------------------------
extern "C" void kernel_launch(void* const* d_in, const int* in_sizes, int n_in,
                              void* d_out, int out_size, void* d_ws, size_t ws_size,
                              hipStream_t stream) {
    const float* x     = (const float*)d_in[0];
    const int*   adj   = (const int*)d_in[1];   // [3][2][N_EDGES]
    const float* Ws    = (const float*)d_in[2]; // [3][256][256]
    const float* a_l   = (const float*)d_in[3]; // [3][8][32]
    const float* a_r   = (const float*)d_in[4];
    const float* bias  = (const float*)d_in[5]; // [3][256]
    const float* att_w = (const float*)d_in[6]; // [256]
    const float* att_b = (const float*)d_in[7]; // [1]
    float* out = (float*)d_out;

    // Workspace layout (~168.6 MB)
    char* w = (char*)d_ws;
    unsigned short* xb = (unsigned short*)w; w += (size_t)N_NODES * W_IN * 2;   // 25.6 MB
    unsigned short* H  = (unsigned short*)w; w += (size_t)N_NODES * W_OUT * 2;  // 25.6 MB
    unsigned short* Wt = (unsigned short*)w; w += (size_t)NUM_T * W_IN * W_OUT * 2; // 0.39 MB
    float* ot0 = (float*)w; w += (size_t)N_NODES * W_OUT * 4;   // 51.2 MB
    float* ot1 = (float*)w; w += (size_t)N_NODES * W_OUT * 4;   // 51.2 MB
    float* el  = (float*)w; w += (size_t)N_NODES * HEADS * 4;   // 1.6 MB
    float* er  = (float*)w; w += (size_t)N_NODES * HEADS * 4;   // 1.6 MB
    int* csr_src = (int*)w; w += (size_t)NUM_T * N_EDGES * 4;   // 9.6 MB
    int* row_ptr = (int*)w; w += (size_t)NUM_T * (N_NODES + 1) * 4;
    int* row_cnt = (int*)w; w += (size_t)NUM_T * N_NODES * 4;
    int* row_cur = (int*)w; w += (size_t)NUM_T * N_NODES * 4;

    float* ot[NUM_T] = {ot0, ot1, out};

    const int edge_blocks = (N_EDGES + 255) / 256;          // 3125
    const int node_wave_blocks = (N_NODES + 3) / 4;         // 12500
    const int gemm_blocks = (N_NODES + 63) / 64;            // 782

    // --- setup (once): converts + CSR build for all 3 types ---
    hipMemsetAsync(row_cnt, 0, (size_t)NUM_T * N_NODES * sizeof(int), stream);
    convert_x<<<12500, 256, 0, stream>>>(x, xb);
    convert_W<<<dim3(256, NUM_T), 256, 0, stream>>>(Ws, Wt);
    count_all<<<dim3(edge_blocks, NUM_T), 256, 0, stream>>>(adj, row_cnt);
    scan_all<<<NUM_T, SCAN_T, 0, stream>>>(row_cnt, row_ptr, row_cur);
    bucket_all<<<dim3(edge_blocks, NUM_T), 256, 0, stream>>>(adj, row_cur, csr_src);

    // --- per edge type: GEMM -> scores -> gather ---
    for (int t = 0; t < NUM_T; ++t) {
        gemm_bf16<<<gemm_blocks, 256, 0, stream>>>(xb, Wt + (size_t)t * W_IN * W_OUT, H);
        node_scores<<<node_wave_blocks, 256, 0, stream>>>(
            H, a_l + t * 256, a_r + t * 256, el, er);
        gat_gather<<<node_wave_blocks, 256, 0, stream>>>(
            csr_src + (size_t)t * N_EDGES, row_ptr + (size_t)t * (N_NODES + 1),
            el, er, H, ot[t]);
    }

    combine<<<node_wave_blocks, 256, 0, stream>>>(ot0, ot1, out, bias, att_w,
                                                  att_b, out);
}

// Round 4
// 538.847 us; speedup vs baseline: 17.4699x; 1.5612x over previous
//
#include <hip/hip_runtime.h>

#define N_NODES 50000
#define W_IN    256
#define W_OUT   256
#define HEADS   8
#define NUM_T   3
#define N_EDGES 800000
#define NEG_SLOPE 0.2f

#define NB      128           // coarse buckets (98 used)
#define BSH     9             // bucket = dst >> 9  (512 nodes/bucket)
#define BNODES  512
#define P1_EPT  16            // edges per thread in partition kernels
#define P1_CHUNK (256 * P1_EPT)   // 4096 edges per block
#define P1_BLOCKS ((N_EDGES + P1_CHUNK - 1) / P1_CHUNK)  // 196
#define NB_USED ((N_NODES + BNODES - 1) / BNODES)        // 98

typedef __attribute__((ext_vector_type(8))) short bf16x8;
typedef __attribute__((ext_vector_type(4))) float f32x4;

__device__ __forceinline__ unsigned short f2b(float f) {
    unsigned u = __float_as_uint(f);
    u = (u + 0x7fffu + ((u >> 16) & 1u)) >> 16;
    return (unsigned short)u;
}

// ---------------------------------------------------------------------------
// x fp32 -> bf16 (RNE). 12500 blocks * 256 threads * 4 elems = 12.8M exact.
// ---------------------------------------------------------------------------
__global__ __launch_bounds__(256) void convert_x(const float* __restrict__ x,
                                                 unsigned short* __restrict__ xb) {
    const size_t i = ((size_t)blockIdx.x * 256 + threadIdx.x) * 4;
    const float4 v = *(const float4*)(x + i);
    ushort4 o;
    o.x = f2b(v.x); o.y = f2b(v.y); o.z = f2b(v.z); o.w = f2b(v.w);
    *(ushort4*)(xb + i) = o;
}

// ---------------------------------------------------------------------------
// W fp32 [t][k][n] -> bf16 transposed [t][n][k].
// ---------------------------------------------------------------------------
__global__ __launch_bounds__(256) void convert_W(const float* __restrict__ Wsrc,
                                                 unsigned short* __restrict__ Wt) {
    const int t = blockIdx.y;
    const int gid = blockIdx.x * 256 + threadIdx.x;  // 0..65535
    const int k = gid >> 8, n = gid & 255;
    Wt[(size_t)t * 65536 + (size_t)n * 256 + k] = f2b(Wsrc[(size_t)t * 65536 + gid]);
}

// ---------------------------------------------------------------------------
// Partition level 1a: coarse histogram (LDS-aggregated).
// ---------------------------------------------------------------------------
__global__ __launch_bounds__(256) void p1_hist(const int* __restrict__ adj,
                                               int* __restrict__ bucket_cnt) {
    __shared__ int lh[NB];
    const int t = blockIdx.y;
    const int tid = threadIdx.x;
    if (tid < NB) lh[tid] = 0;
    __syncthreads();

    const int* dstp = adj + (size_t)t * 2 * N_EDGES + N_EDGES;
    const int e0 = blockIdx.x * P1_CHUNK + tid * P1_EPT;
#pragma unroll
    for (int i = 0; i < P1_EPT; ++i) {
        const int e = e0 + i;
        if (e < N_EDGES) atomicAdd(&lh[dstp[e] >> BSH], 1);
    }
    __syncthreads();
    if (tid < NB && lh[tid] > 0) atomicAdd(&bucket_cnt[t * NB + tid], lh[tid]);
}

// ---------------------------------------------------------------------------
// Partition level 1b: scan 128 bucket counts per type. One block, 128 thr.
// ---------------------------------------------------------------------------
__global__ __launch_bounds__(128) void p1_scan(const int* __restrict__ bucket_cnt,
                                               int* __restrict__ bucket_ptr,
                                               int* __restrict__ bucket_cur) {
    __shared__ int s[NB];
    const int tid = threadIdx.x;
    for (int t = 0; t < NUM_T; ++t) {
        const int v = bucket_cnt[t * NB + tid];
        s[tid] = v;
        __syncthreads();
        for (int off = 1; off < NB; off <<= 1) {
            int o = (tid >= off) ? s[tid - off] : 0;
            __syncthreads();
            s[tid] += o;
            __syncthreads();
        }
        const int incl = s[tid];
        const int excl = incl - v;
        bucket_ptr[t * (NB + 1) + tid] = excl;
        bucket_cur[t * NB + tid] = excl;
        if (tid == NB - 1) bucket_ptr[t * (NB + 1) + NB] = incl;
        __syncthreads();
    }
}

// ---------------------------------------------------------------------------
// Partition level 1c: scatter (src,dst) pairs into coarse buckets.
// Per-block LDS ranking -> one global atomic per (block,bucket) -> writes
// land in contiguous ~340B windows per bucket (low write amplification).
// ---------------------------------------------------------------------------
__global__ __launch_bounds__(256) void p1_scatter(const int* __restrict__ adj,
                                                  int* __restrict__ bucket_cur,
                                                  uint2* __restrict__ part) {
    __shared__ int lh[NB];
    __shared__ int lbase[NB];
    const int t = blockIdx.y;
    const int tid = threadIdx.x;
    if (tid < NB) lh[tid] = 0;
    __syncthreads();

    const int* srcp = adj + (size_t)t * 2 * N_EDGES;
    const int* dstp = srcp + N_EDGES;
    const int e0 = blockIdx.x * P1_CHUNK + tid * P1_EPT;

    int es[P1_EPT], ed[P1_EPT], rk[P1_EPT];
#pragma unroll
    for (int i = 0; i < P1_EPT; ++i) {
        const int e = e0 + i;
        if (e < N_EDGES) {
            es[i] = srcp[e];
            ed[i] = dstp[e];
            rk[i] = atomicAdd(&lh[ed[i] >> BSH], 1);
        } else {
            ed[i] = -1;
        }
    }
    __syncthreads();
    if (tid < NB && lh[tid] > 0)
        lbase[tid] = atomicAdd(&bucket_cur[t * NB + tid], lh[tid]);
    __syncthreads();

    uint2* pt = part + (size_t)t * N_EDGES;
#pragma unroll
    for (int i = 0; i < P1_EPT; ++i) {
        if (ed[i] >= 0) {
            const int b = ed[i] >> BSH;
            pt[lbase[b] + rk[i]] = make_uint2((unsigned)es[i], (unsigned)ed[i]);
        }
    }
}

// ---------------------------------------------------------------------------
// Partition level 2: per-bucket local CSR. One block per (bucket, type).
// Counts + scan in LDS; emits row_ptr (coalesced) and csr_src inside the
// bucket's private contiguous window. Replaces global count+scan+bucket.
// ---------------------------------------------------------------------------
__global__ __launch_bounds__(256) void p2_csr(const uint2* __restrict__ part,
                                              const int* __restrict__ bucket_ptr,
                                              int* __restrict__ row_ptr_all,
                                              int* __restrict__ csr_all) {
    __shared__ int sc[BNODES];
    const int b = blockIdx.x;
    const int t = blockIdx.y;
    const int tid = threadIdx.x;
    const int lane = tid & 63;
    const int wave = tid >> 6;

    const uint2* pt = part + (size_t)t * N_EDGES;
    int* row_ptr = row_ptr_all + (size_t)t * (N_NODES + 1);
    int* csr = csr_all + (size_t)t * N_EDGES;

    const int bp0 = bucket_ptr[t * (NB + 1) + b];
    const int bp1 = bucket_ptr[t * (NB + 1) + b + 1];
    const int node0 = b * BNODES;
    int nn = N_NODES - node0; if (nn > BNODES) nn = BNODES;

    sc[tid] = 0; sc[tid + 256] = 0;
    __syncthreads();

    for (int idx = bp0 + tid; idx < bp1; idx += 256)
        atomicAdd(&sc[pt[idx].y - node0], 1);
    __syncthreads();

    // exclusive scan of 512 by wave 0 (8 per lane + shfl wave-scan)
    if (wave == 0) {
        int v[8], ex[8];
        int s = 0;
#pragma unroll
        for (int i = 0; i < 8; ++i) { v[i] = sc[lane * 8 + i]; ex[i] = s; s += v[i]; }
        int run = s;
        for (int off = 1; off < 64; off <<= 1) {
            int o = __shfl_up(run, off);
            if (lane >= off) run += o;
        }
        const int base = run - s;
#pragma unroll
        for (int i = 0; i < 8; ++i) sc[lane * 8 + i] = base + ex[i];
    }
    __syncthreads();

    // row_ptr for this bucket's nodes
    for (int i = tid; i < nn; i += 256) row_ptr[node0 + i] = bp0 + sc[i];
    if (b == NB_USED - 1 && tid == 0) row_ptr[N_NODES] = N_EDGES;
    __syncthreads();

    // bucket src ids; sc doubles as running cursor (starts at prefix)
    for (int idx = bp0 + tid; idx < bp1; idx += 256) {
        const uint2 e = pt[idx];
        const int pos = bp0 + atomicAdd(&sc[e.y - node0], 1);
        csr[pos] = (int)e.x;
    }
}

// ---------------------------------------------------------------------------
// GEMM + fused attention scores. H = xb @ W (bf16 MFMA 16x16x32), tile
// 64m x 256n, BK=32, 4 waves (wave w owns cols [64w,64w+64) = heads 2w,2w+1).
// Epilogue computes el/er per (row, head) with in-wave reductions only.
// ---------------------------------------------------------------------------
__global__ __launch_bounds__(256) void gemm_fused(const unsigned short* __restrict__ xb,
                                                  const unsigned short* __restrict__ Wt,
                                                  const float* __restrict__ al,
                                                  const float* __restrict__ ar,
                                                  unsigned short* __restrict__ H,
                                                  float* __restrict__ el,
                                                  float* __restrict__ er) {
    __shared__ unsigned short As[64 * 40];
    __shared__ unsigned short Bs[256 * 40];
    __shared__ float els[64 * 8];
    __shared__ float ers[64 * 8];

    const int tid = threadIdx.x;
    const int wave = tid >> 6;
    const int lane = tid & 63;
    const int quad = lane >> 4;
    const int l16 = lane & 15;
    const int m0 = blockIdx.x * 64;

    f32x4 acc[4][4] = {};

    const int arow = tid >> 2;
    const int achunk = (tid & 3) * 8;
    int gm = m0 + arow;
    if (gm > N_NODES - 1) gm = N_NODES - 1;
    const unsigned short* aptr = xb + (size_t)gm * W_IN + achunk;

    for (int k0 = 0; k0 < W_IN; k0 += 32) {
        const uint4 av = *(const uint4*)(aptr + k0);
        *(uint4*)&As[arow * 40 + achunk] = av;
#pragma unroll
        for (int i = 0; i < 4; ++i) {
            const int idx = i * 256 + tid;
            const int brow = idx >> 2;
            const int bch = (idx & 3) * 8;
            const uint4 bv = *(const uint4*)(Wt + (size_t)brow * W_IN + k0 + bch);
            *(uint4*)&Bs[brow * 40 + bch] = bv;
        }
        __syncthreads();

        bf16x8 af[4], bfr[4];
#pragma unroll
        for (int mi = 0; mi < 4; ++mi)
            af[mi] = *(const bf16x8*)&As[(mi * 16 + l16) * 40 + quad * 8];
#pragma unroll
        for (int ni = 0; ni < 4; ++ni)
            bfr[ni] = *(const bf16x8*)&Bs[(wave * 64 + ni * 16 + l16) * 40 + quad * 8];
#pragma unroll
        for (int mi = 0; mi < 4; ++mi)
#pragma unroll
            for (int ni = 0; ni < 4; ++ni)
                acc[mi][ni] = __builtin_amdgcn_mfma_f32_16x16x32_bf16(
                    af[mi], bfr[ni], acc[mi][ni], 0, 0, 0);
        __syncthreads();
    }

    // --- H store (C/D: col = l16, row = quad*4+reg) ---
#pragma unroll
    for (int mi = 0; mi < 4; ++mi)
#pragma unroll
        for (int reg = 0; reg < 4; ++reg) {
            const int gr = m0 + mi * 16 + quad * 4 + reg;
            if (gr < N_NODES)
#pragma unroll
                for (int ni = 0; ni < 4; ++ni)
                    H[(size_t)gr * W_OUT + wave * 64 + ni * 16 + l16] =
                        f2b(acc[mi][ni][reg]);
        }

    // --- fused el/er: lane's cols c(ni) = wave*64 + ni*16 + l16, head = c>>5
    float al4[4], ar4[4];
#pragma unroll
    for (int ni = 0; ni < 4; ++ni) {
        const int c = wave * 64 + ni * 16 + l16;
        al4[ni] = al[c];
        ar4[ni] = ar[c];
    }
#pragma unroll
    for (int mi = 0; mi < 4; ++mi) {
        float pl[4][2] = {}, pr[4][2] = {};
#pragma unroll
        for (int ni = 0; ni < 4; ++ni) {
            const int hl = ni >> 1;
#pragma unroll
            for (int reg = 0; reg < 4; ++reg) {
                pl[reg][hl] += acc[mi][ni][reg] * al4[ni];
                pr[reg][hl] += acc[mi][ni][reg] * ar4[ni];
            }
        }
#pragma unroll
        for (int off = 1; off < 16; off <<= 1)
#pragma unroll
            for (int reg = 0; reg < 4; ++reg)
#pragma unroll
                for (int hl = 0; hl < 2; ++hl) {
                    pl[reg][hl] += __shfl_xor(pl[reg][hl], off);
                    pr[reg][hl] += __shfl_xor(pr[reg][hl], off);
                }
        if (l16 == 0)
#pragma unroll
            for (int reg = 0; reg < 4; ++reg)
#pragma unroll
                for (int hl = 0; hl < 2; ++hl) {
                    const int row = mi * 16 + quad * 4 + reg;
                    els[row * 8 + wave * 2 + hl] = pl[reg][hl];
                    ers[row * 8 + wave * 2 + hl] = pr[reg][hl];
                }
    }
    __syncthreads();

    int nn = N_NODES - m0; if (nn > 64) nn = 64;
    const int nn8 = nn * 8;
    const int i = tid * 4;
    if (i < nn8) {
        *(float4*)(el + (size_t)m0 * 8 + i) = *(float4*)&els[i];
        *(float4*)(er + (size_t)m0 * 8 + i) = *(float4*)&ers[i];
    }
}

// ---------------------------------------------------------------------------
// Fused denominator + weighted gather, bf16 rows. One wave per dst node.
// ---------------------------------------------------------------------------
__global__ __launch_bounds__(256) void gat_gather(const int* __restrict__ csr_src,
                                                  const int* __restrict__ row_ptr,
                                                  const float* __restrict__ el,
                                                  const float* __restrict__ er,
                                                  const unsigned short* __restrict__ H,
                                                  float* __restrict__ ot) {
    const int node = (blockIdx.x * blockDim.x + threadIdx.x) >> 6;
    const int lane = threadIdx.x & 63;
    if (node >= N_NODES) return;
    const int hh = lane >> 3;

    const int beg = row_ptr[node];
    const int end = row_ptr[node + 1];
    const float erv = er[(size_t)node * HEADS + hh];

    float4 acc = make_float4(0.f, 0.f, 0.f, 0.f);
    float ssum = 0.f;

    for (int j0 = beg; j0 < end; j0 += 64) {
        int nsrc = end - j0;
        if (nsrc > 64) nsrc = 64;
        int mysrc = 0;
        if (j0 + lane < end) mysrc = csr_src[j0 + lane];

        for (int j = 0; j < nsrc; ++j) {
            const int src = __shfl(mysrc, j);
            float v = el[(size_t)src * HEADS + hh] + erv;
            v = (v > 0.f) ? v : NEG_SLOPE * v;
            const float w = __expf(v);
            const uint2 u = *(const uint2*)(H + (size_t)src * W_OUT + lane * 4);
            acc.x += w * __uint_as_float(u.x << 16);
            acc.y += w * __uint_as_float(u.x & 0xffff0000u);
            acc.z += w * __uint_as_float(u.y << 16);
            acc.w += w * __uint_as_float(u.y & 0xffff0000u);
            ssum += w;
        }
    }

    const float inv = 1.f / (ssum + 1e-9f);
    float4 o = make_float4(acc.x * inv, acc.y * inv, acc.z * inv, acc.w * inv);
    *(float4*)(ot + (size_t)node * W_OUT + lane * 4) = o;
}

// ---------------------------------------------------------------------------
// Semantic attention combine (ot2 == out fp32, in place).
// ---------------------------------------------------------------------------
__global__ __launch_bounds__(256) void combine(const float* __restrict__ ot0,
                                               const float* __restrict__ ot1,
                                               const float* __restrict__ ot2,
                                               const float* __restrict__ bias,
                                               const float* __restrict__ att_w,
                                               const float* __restrict__ att_b,
                                               float* __restrict__ out) {
    const int gw = (blockIdx.x * blockDim.x + threadIdx.x) >> 6;
    const int lane = threadIdx.x & 63;
    if (gw >= N_NODES) return;

    const float4 aw = *(const float4*)(att_w + lane * 4);
    const size_t base = (size_t)gw * W_OUT + lane * 4;

    float4 v[NUM_T];
    float p[NUM_T];
    const float* ots[NUM_T] = {ot0, ot1, ot2};
#pragma unroll
    for (int t = 0; t < NUM_T; ++t) {
        float4 hv = *(const float4*)(ots[t] + base);
        const float4 bv = *(const float4*)(bias + t * W_OUT + lane * 4);
        hv.x += bv.x; hv.y += bv.y; hv.z += bv.z; hv.w += bv.w;
        v[t] = hv;
        p[t] = hv.x * aw.x + hv.y * aw.y + hv.z * aw.z + hv.w * aw.w;
    }
#pragma unroll
    for (int off = 1; off < 64; off <<= 1) {
        p[0] += __shfl_xor(p[0], off);
        p[1] += __shfl_xor(p[1], off);
        p[2] += __shfl_xor(p[2], off);
    }
    const float ab = att_b[0];
    const float a0 = p[0] + ab, a1 = p[1] + ab, a2 = p[2] + ab;
    float4 o;
    o.x = a0 * v[0].x + a1 * v[1].x + a2 * v[2].x;
    o.y = a0 * v[0].y + a1 * v[1].y + a2 * v[2].y;
    o.z = a0 * v[0].z + a1 * v[1].z + a2 * v[2].z;
    o.w = a0 * v[0].w + a1 * v[1].w + a2 * v[2].w;
    *(float4*)(out + base) = o;
}

// ---------------------------------------------------------------------------
extern "C" void kernel_launch(void* const* d_in, const int* in_sizes, int n_in,
                              void* d_out, int out_size, void* d_ws, size_t ws_size,
                              hipStream_t stream) {
    const float* x     = (const float*)d_in[0];
    const int*   adj   = (const int*)d_in[1];   // [3][2][N_EDGES]
    const float* Ws    = (const float*)d_in[2]; // [3][256][256]
    const float* a_l   = (const float*)d_in[3]; // [3][8][32]
    const float* a_r   = (const float*)d_in[4];
    const float* bias  = (const float*)d_in[5]; // [3][256]
    const float* att_w = (const float*)d_in[6]; // [256]
    const float* att_b = (const float*)d_in[7]; // [1]
    float* out = (float*)d_out;

    // Workspace (~170 MB). part aliases ot0: part is fully consumed by p2_csr
    // before gat_gather(t=0) writes ot0 (single stream, sequential).
    char* w = (char*)d_ws;
    unsigned short* xb = (unsigned short*)w; w += (size_t)N_NODES * W_IN * 2;   // 25.6 MB
    unsigned short* H  = (unsigned short*)w; w += (size_t)N_NODES * W_OUT * 2;  // 25.6 MB
    unsigned short* Wt = (unsigned short*)w; w += (size_t)NUM_T * 65536 * 2;    // 0.39 MB
    float* ot0 = (float*)w; w += (size_t)N_NODES * W_OUT * 4;   // 51.2 MB
    float* ot1 = (float*)w; w += (size_t)N_NODES * W_OUT * 4;   // 51.2 MB
    float* el  = (float*)w; w += (size_t)N_NODES * HEADS * 4;   // 1.6 MB
    float* er  = (float*)w; w += (size_t)N_NODES * HEADS * 4;   // 1.6 MB
    int* csr_src = (int*)w; w += (size_t)NUM_T * N_EDGES * 4;   // 9.6 MB
    int* row_ptr = (int*)w; w += (size_t)NUM_T * (N_NODES + 1) * 4;
    int* bucket_cnt = (int*)w; w += NUM_T * NB * 4;
    int* bucket_ptr = (int*)w; w += NUM_T * (NB + 1) * 4;
    int* bucket_cur = (int*)w; w += NUM_T * NB * 4;
    uint2* part = (uint2*)ot0;   // 19.2 MB alias

    float* ot[NUM_T] = {ot0, ot1, out};
    const int node_wave_blocks = (N_NODES + 3) / 4;  // 12500
    const int gemm_blocks = (N_NODES + 63) / 64;     // 782

    // --- setup: converts + two-level CSR build (all types at once) ---
    hipMemsetAsync(bucket_cnt, 0, NUM_T * NB * sizeof(int), stream);
    convert_x<<<12500, 256, 0, stream>>>(x, xb);
    convert_W<<<dim3(256, NUM_T), 256, 0, stream>>>(Ws, Wt);
    p1_hist<<<dim3(P1_BLOCKS, NUM_T), 256, 0, stream>>>(adj, bucket_cnt);
    p1_scan<<<1, 128, 0, stream>>>(bucket_cnt, bucket_ptr, bucket_cur);
    p1_scatter<<<dim3(P1_BLOCKS, NUM_T), 256, 0, stream>>>(adj, bucket_cur, part);
    p2_csr<<<dim3(NB_USED, NUM_T), 256, 0, stream>>>(part, bucket_ptr, row_ptr,
                                                     csr_src);

    // --- per edge type: fused GEMM+scores -> gather ---
    for (int t = 0; t < NUM_T; ++t) {
        gemm_fused<<<gemm_blocks, 256, 0, stream>>>(
            xb, Wt + (size_t)t * 65536, a_l + t * 256, a_r + t * 256, H, el, er);
        gat_gather<<<node_wave_blocks, 256, 0, stream>>>(
            csr_src + (size_t)t * N_EDGES, row_ptr + (size_t)t * (N_NODES + 1),
            el, er, H, ot[t]);
    }

    combine<<<node_wave_blocks, 256, 0, stream>>>(ot0, ot1, out, bias, att_w,
                                                  att_b, out);
}

// Round 5
// 523.306 us; speedup vs baseline: 17.9887x; 1.0297x over previous
//
#include <hip/hip_runtime.h>

#define N_NODES 50000
#define W_IN    256
#define W_OUT   256
#define HEADS   8
#define NUM_T   3
#define N_EDGES 800000
#define NEG_SLOPE 0.2f

#define NB      128           // coarse buckets (98 used)
#define BSH     9             // bucket = dst >> 9  (512 nodes/bucket)
#define BNODES  512
#define P1_EPT  16            // edges per thread in partition kernels
#define P1_CHUNK (256 * P1_EPT)   // 4096 edges per block
#define P1_BLOCKS ((N_EDGES + P1_CHUNK - 1) / P1_CHUNK)  // 196
#define NB_USED ((N_NODES + BNODES - 1) / BNODES)        // 98

typedef __attribute__((ext_vector_type(8))) short bf16x8;
typedef __attribute__((ext_vector_type(4))) float f32x4;

__device__ __forceinline__ unsigned short f2b(float f) {
    unsigned u = __float_as_uint(f);
    u = (u + 0x7fffu + ((u >> 16) & 1u)) >> 16;
    return (unsigned short)u;
}
__device__ __forceinline__ float blo(unsigned u) { return __uint_as_float(u << 16); }
__device__ __forceinline__ float bhi(unsigned u) { return __uint_as_float(u & 0xffff0000u); }

// ---------------------------------------------------------------------------
// x fp32 -> bf16 (RNE). 12500 blocks * 256 threads * 4 elems = 12.8M exact.
// ---------------------------------------------------------------------------
__global__ __launch_bounds__(256) void convert_x(const float* __restrict__ x,
                                                 unsigned short* __restrict__ xb) {
    const size_t i = ((size_t)blockIdx.x * 256 + threadIdx.x) * 4;
    const float4 v = *(const float4*)(x + i);
    ushort4 o;
    o.x = f2b(v.x); o.y = f2b(v.y); o.z = f2b(v.z); o.w = f2b(v.w);
    *(ushort4*)(xb + i) = o;
}

// ---------------------------------------------------------------------------
// W fp32 [t][k][n] -> bf16 transposed [t][n][k].
// ---------------------------------------------------------------------------
__global__ __launch_bounds__(256) void convert_W(const float* __restrict__ Wsrc,
                                                 unsigned short* __restrict__ Wt) {
    const int t = blockIdx.y;
    const int gid = blockIdx.x * 256 + threadIdx.x;  // 0..65535
    const int k = gid >> 8, n = gid & 255;
    Wt[(size_t)t * 65536 + (size_t)n * 256 + k] = f2b(Wsrc[(size_t)t * 65536 + gid]);
}

// ---------------------------------------------------------------------------
// Partition level 1a: coarse histogram (LDS-aggregated).
// ---------------------------------------------------------------------------
__global__ __launch_bounds__(256) void p1_hist(const int* __restrict__ adj,
                                               int* __restrict__ bucket_cnt) {
    __shared__ int lh[NB];
    const int t = blockIdx.y;
    const int tid = threadIdx.x;
    if (tid < NB) lh[tid] = 0;
    __syncthreads();

    const int* dstp = adj + (size_t)t * 2 * N_EDGES + N_EDGES;
    const int e0 = blockIdx.x * P1_CHUNK + tid * P1_EPT;
#pragma unroll
    for (int i = 0; i < P1_EPT; ++i) {
        const int e = e0 + i;
        if (e < N_EDGES) atomicAdd(&lh[dstp[e] >> BSH], 1);
    }
    __syncthreads();
    if (tid < NB && lh[tid] > 0) atomicAdd(&bucket_cnt[t * NB + tid], lh[tid]);
}

// ---------------------------------------------------------------------------
// Partition level 1b: scan 128 bucket counts per type. One block, 128 thr.
// ---------------------------------------------------------------------------
__global__ __launch_bounds__(128) void p1_scan(const int* __restrict__ bucket_cnt,
                                               int* __restrict__ bucket_ptr,
                                               int* __restrict__ bucket_cur) {
    __shared__ int s[NB];
    const int tid = threadIdx.x;
    for (int t = 0; t < NUM_T; ++t) {
        const int v = bucket_cnt[t * NB + tid];
        s[tid] = v;
        __syncthreads();
        for (int off = 1; off < NB; off <<= 1) {
            int o = (tid >= off) ? s[tid - off] : 0;
            __syncthreads();
            s[tid] += o;
            __syncthreads();
        }
        const int incl = s[tid];
        const int excl = incl - v;
        bucket_ptr[t * (NB + 1) + tid] = excl;
        bucket_cur[t * NB + tid] = excl;
        if (tid == NB - 1) bucket_ptr[t * (NB + 1) + NB] = incl;
        __syncthreads();
    }
}

// ---------------------------------------------------------------------------
// Partition level 1c: scatter (src,dst) pairs into coarse buckets.
// ---------------------------------------------------------------------------
__global__ __launch_bounds__(256) void p1_scatter(const int* __restrict__ adj,
                                                  int* __restrict__ bucket_cur,
                                                  uint2* __restrict__ part) {
    __shared__ int lh[NB];
    __shared__ int lbase[NB];
    const int t = blockIdx.y;
    const int tid = threadIdx.x;
    if (tid < NB) lh[tid] = 0;
    __syncthreads();

    const int* srcp = adj + (size_t)t * 2 * N_EDGES;
    const int* dstp = srcp + N_EDGES;
    const int e0 = blockIdx.x * P1_CHUNK + tid * P1_EPT;

    int es[P1_EPT], ed[P1_EPT], rk[P1_EPT];
#pragma unroll
    for (int i = 0; i < P1_EPT; ++i) {
        const int e = e0 + i;
        if (e < N_EDGES) {
            es[i] = srcp[e];
            ed[i] = dstp[e];
            rk[i] = atomicAdd(&lh[ed[i] >> BSH], 1);
        } else {
            ed[i] = -1;
        }
    }
    __syncthreads();
    if (tid < NB && lh[tid] > 0)
        lbase[tid] = atomicAdd(&bucket_cur[t * NB + tid], lh[tid]);
    __syncthreads();

    uint2* pt = part + (size_t)t * N_EDGES;
#pragma unroll
    for (int i = 0; i < P1_EPT; ++i) {
        if (ed[i] >= 0) {
            const int b = ed[i] >> BSH;
            pt[lbase[b] + rk[i]] = make_uint2((unsigned)es[i], (unsigned)ed[i]);
        }
    }
}

// ---------------------------------------------------------------------------
// Partition level 2: per-bucket local CSR. One block per (bucket, type).
// ---------------------------------------------------------------------------
__global__ __launch_bounds__(256) void p2_csr(const uint2* __restrict__ part,
                                              const int* __restrict__ bucket_ptr,
                                              int* __restrict__ row_ptr_all,
                                              int* __restrict__ csr_all) {
    __shared__ int sc[BNODES];
    const int b = blockIdx.x;
    const int t = blockIdx.y;
    const int tid = threadIdx.x;
    const int lane = tid & 63;
    const int wave = tid >> 6;

    const uint2* pt = part + (size_t)t * N_EDGES;
    int* row_ptr = row_ptr_all + (size_t)t * (N_NODES + 1);
    int* csr = csr_all + (size_t)t * N_EDGES;

    const int bp0 = bucket_ptr[t * (NB + 1) + b];
    const int bp1 = bucket_ptr[t * (NB + 1) + b + 1];
    const int node0 = b * BNODES;
    int nn = N_NODES - node0; if (nn > BNODES) nn = BNODES;

    sc[tid] = 0; sc[tid + 256] = 0;
    __syncthreads();

    for (int idx = bp0 + tid; idx < bp1; idx += 256)
        atomicAdd(&sc[pt[idx].y - node0], 1);
    __syncthreads();

    if (wave == 0) {
        int v[8], ex[8];
        int s = 0;
#pragma unroll
        for (int i = 0; i < 8; ++i) { v[i] = sc[lane * 8 + i]; ex[i] = s; s += v[i]; }
        int run = s;
        for (int off = 1; off < 64; off <<= 1) {
            int o = __shfl_up(run, off);
            if (lane >= off) run += o;
        }
        const int base = run - s;
#pragma unroll
        for (int i = 0; i < 8; ++i) sc[lane * 8 + i] = base + ex[i];
    }
    __syncthreads();

    for (int i = tid; i < nn; i += 256) row_ptr[node0 + i] = bp0 + sc[i];
    if (b == NB_USED - 1 && tid == 0) row_ptr[N_NODES] = N_EDGES;
    __syncthreads();

    for (int idx = bp0 + tid; idx < bp1; idx += 256) {
        const uint2 e = pt[idx];
        const int pos = bp0 + atomicAdd(&sc[e.y - node0], 1);
        csr[pos] = (int)e.x;
    }
}

// ---------------------------------------------------------------------------
// GEMM + fused attention scores (unchanged from round 4).
// ---------------------------------------------------------------------------
__global__ __launch_bounds__(256) void gemm_fused(const unsigned short* __restrict__ xb,
                                                  const unsigned short* __restrict__ Wt,
                                                  const float* __restrict__ al,
                                                  const float* __restrict__ ar,
                                                  unsigned short* __restrict__ H,
                                                  float* __restrict__ el,
                                                  float* __restrict__ er) {
    __shared__ unsigned short As[64 * 40];
    __shared__ unsigned short Bs[256 * 40];
    __shared__ float els[64 * 8];
    __shared__ float ers[64 * 8];

    const int tid = threadIdx.x;
    const int wave = tid >> 6;
    const int lane = tid & 63;
    const int quad = lane >> 4;
    const int l16 = lane & 15;
    const int m0 = blockIdx.x * 64;

    f32x4 acc[4][4] = {};

    const int arow = tid >> 2;
    const int achunk = (tid & 3) * 8;
    int gm = m0 + arow;
    if (gm > N_NODES - 1) gm = N_NODES - 1;
    const unsigned short* aptr = xb + (size_t)gm * W_IN + achunk;

    for (int k0 = 0; k0 < W_IN; k0 += 32) {
        const uint4 av = *(const uint4*)(aptr + k0);
        *(uint4*)&As[arow * 40 + achunk] = av;
#pragma unroll
        for (int i = 0; i < 4; ++i) {
            const int idx = i * 256 + tid;
            const int brow = idx >> 2;
            const int bch = (idx & 3) * 8;
            const uint4 bv = *(const uint4*)(Wt + (size_t)brow * W_IN + k0 + bch);
            *(uint4*)&Bs[brow * 40 + bch] = bv;
        }
        __syncthreads();

        bf16x8 af[4], bfr[4];
#pragma unroll
        for (int mi = 0; mi < 4; ++mi)
            af[mi] = *(const bf16x8*)&As[(mi * 16 + l16) * 40 + quad * 8];
#pragma unroll
        for (int ni = 0; ni < 4; ++ni)
            bfr[ni] = *(const bf16x8*)&Bs[(wave * 64 + ni * 16 + l16) * 40 + quad * 8];
#pragma unroll
        for (int mi = 0; mi < 4; ++mi)
#pragma unroll
            for (int ni = 0; ni < 4; ++ni)
                acc[mi][ni] = __builtin_amdgcn_mfma_f32_16x16x32_bf16(
                    af[mi], bfr[ni], acc[mi][ni], 0, 0, 0);
        __syncthreads();
    }

#pragma unroll
    for (int mi = 0; mi < 4; ++mi)
#pragma unroll
        for (int reg = 0; reg < 4; ++reg) {
            const int gr = m0 + mi * 16 + quad * 4 + reg;
            if (gr < N_NODES)
#pragma unroll
                for (int ni = 0; ni < 4; ++ni)
                    H[(size_t)gr * W_OUT + wave * 64 + ni * 16 + l16] =
                        f2b(acc[mi][ni][reg]);
        }

    float al4[4], ar4[4];
#pragma unroll
    for (int ni = 0; ni < 4; ++ni) {
        const int c = wave * 64 + ni * 16 + l16;
        al4[ni] = al[c];
        ar4[ni] = ar[c];
    }
#pragma unroll
    for (int mi = 0; mi < 4; ++mi) {
        float pl[4][2] = {}, pr[4][2] = {};
#pragma unroll
        for (int ni = 0; ni < 4; ++ni) {
            const int hl = ni >> 1;
#pragma unroll
            for (int reg = 0; reg < 4; ++reg) {
                pl[reg][hl] += acc[mi][ni][reg] * al4[ni];
                pr[reg][hl] += acc[mi][ni][reg] * ar4[ni];
            }
        }
#pragma unroll
        for (int off = 1; off < 16; off <<= 1)
#pragma unroll
            for (int reg = 0; reg < 4; ++reg)
#pragma unroll
                for (int hl = 0; hl < 2; ++hl) {
                    pl[reg][hl] += __shfl_xor(pl[reg][hl], off);
                    pr[reg][hl] += __shfl_xor(pr[reg][hl], off);
                }
        if (l16 == 0)
#pragma unroll
            for (int reg = 0; reg < 4; ++reg)
#pragma unroll
                for (int hl = 0; hl < 2; ++hl) {
                    const int row = mi * 16 + quad * 4 + reg;
                    els[row * 8 + wave * 2 + hl] = pl[reg][hl];
                    ers[row * 8 + wave * 2 + hl] = pr[reg][hl];
                }
    }
    __syncthreads();

    int nn = N_NODES - m0; if (nn > 64) nn = 64;
    const int nn8 = nn * 8;
    const int i = tid * 4;
    if (i < nn8) {
        *(float4*)(el + (size_t)m0 * 8 + i) = *(float4*)&els[i];
        *(float4*)(er + (size_t)m0 * 8 + i) = *(float4*)&ers[i];
    }
}

// ---------------------------------------------------------------------------
// Gather v2: one wave per dst node, TWO edges per wave-instruction.
// lane = half*32 + d8; half = edge slot, d8 covers dims 8*d8..8*d8+7 (uint4),
// head = d8>>2. Cross-half reduction at the end; bf16 output row.
// ---------------------------------------------------------------------------
__global__ __launch_bounds__(256) void gat_gather(const int* __restrict__ csr_src,
                                                  const int* __restrict__ row_ptr,
                                                  const float* __restrict__ el,
                                                  const float* __restrict__ er,
                                                  const unsigned short* __restrict__ H,
                                                  unsigned short* __restrict__ ot) {
    const int node = (blockIdx.x * blockDim.x + threadIdx.x) >> 6;
    const int lane = threadIdx.x & 63;
    if (node >= N_NODES) return;
    const int half = lane >> 5;
    const int d8 = lane & 31;
    const int hh = d8 >> 2;

    const int beg = row_ptr[node];
    const int end = row_ptr[node + 1];
    const float erv = er[(size_t)node * HEADS + hh];

    float acc[8] = {};
    float ssum = 0.f;

    for (int j0 = beg; j0 < end; j0 += 64) {
        int navail = end - j0;
        if (navail > 64) navail = 64;
        int mysrc = 0;
        if (j0 + lane < end) mysrc = csr_src[j0 + lane];

        const int npairs = (navail + 1) >> 1;
        for (int p = 0; p < npairs; ++p) {
            const int ei = 2 * p + half;
            const int src = __shfl(mysrc, ei);   // ei<=63; inactive -> src 0
            float v = el[(size_t)src * HEADS + hh] + erv;
            v = (v > 0.f) ? v : NEG_SLOPE * v;
            const float w = (ei < navail) ? __expf(v) : 0.f;
            const uint4 u = *(const uint4*)(H + (size_t)src * W_OUT + d8 * 8);
            acc[0] += w * blo(u.x);
            acc[1] += w * bhi(u.x);
            acc[2] += w * blo(u.y);
            acc[3] += w * bhi(u.y);
            acc[4] += w * blo(u.z);
            acc[5] += w * bhi(u.z);
            acc[6] += w * blo(u.w);
            acc[7] += w * bhi(u.w);
            ssum += w;
        }
    }

#pragma unroll
    for (int i = 0; i < 8; ++i) acc[i] += __shfl_xor(acc[i], 32);
    ssum += __shfl_xor(ssum, 32);

    if (half == 0) {
        const float inv = 1.f / (ssum + 1e-9f);
        unsigned short o8[8];
#pragma unroll
        for (int i = 0; i < 8; ++i) o8[i] = f2b(acc[i] * inv);
        *(uint4*)(ot + (size_t)node * W_OUT + d8 * 8) = *(const uint4*)o8;
    }
}

// ---------------------------------------------------------------------------
// Semantic attention combine: bf16 ot inputs, fp32 out.
// ---------------------------------------------------------------------------
__global__ __launch_bounds__(256) void combine(const unsigned short* __restrict__ ot0,
                                               const unsigned short* __restrict__ ot1,
                                               const unsigned short* __restrict__ ot2,
                                               const float* __restrict__ bias,
                                               const float* __restrict__ att_w,
                                               const float* __restrict__ att_b,
                                               float* __restrict__ out) {
    const int gw = (blockIdx.x * blockDim.x + threadIdx.x) >> 6;
    const int lane = threadIdx.x & 63;
    if (gw >= N_NODES) return;

    const float4 aw = *(const float4*)(att_w + lane * 4);
    const size_t base = (size_t)gw * W_OUT + lane * 4;

    float4 v[NUM_T];
    float p[NUM_T];
    const unsigned short* ots[NUM_T] = {ot0, ot1, ot2};
#pragma unroll
    for (int t = 0; t < NUM_T; ++t) {
        const uint2 u = *(const uint2*)(ots[t] + base);
        const float4 bv = *(const float4*)(bias + t * W_OUT + lane * 4);
        float4 hv;
        hv.x = blo(u.x) + bv.x;
        hv.y = bhi(u.x) + bv.y;
        hv.z = blo(u.y) + bv.z;
        hv.w = bhi(u.y) + bv.w;
        v[t] = hv;
        p[t] = hv.x * aw.x + hv.y * aw.y + hv.z * aw.z + hv.w * aw.w;
    }
#pragma unroll
    for (int off = 1; off < 64; off <<= 1) {
        p[0] += __shfl_xor(p[0], off);
        p[1] += __shfl_xor(p[1], off);
        p[2] += __shfl_xor(p[2], off);
    }
    const float ab = att_b[0];
    const float a0 = p[0] + ab, a1 = p[1] + ab, a2 = p[2] + ab;
    float4 o;
    o.x = a0 * v[0].x + a1 * v[1].x + a2 * v[2].x;
    o.y = a0 * v[0].y + a1 * v[1].y + a2 * v[2].y;
    o.z = a0 * v[0].z + a1 * v[1].z + a2 * v[2].z;
    o.w = a0 * v[0].w + a1 * v[1].w + a2 * v[2].w;
    *(float4*)(out + base) = o;
}

// ---------------------------------------------------------------------------
extern "C" void kernel_launch(void* const* d_in, const int* in_sizes, int n_in,
                              void* d_out, int out_size, void* d_ws, size_t ws_size,
                              hipStream_t stream) {
    const float* x     = (const float*)d_in[0];
    const int*   adj   = (const int*)d_in[1];   // [3][2][N_EDGES]
    const float* Ws    = (const float*)d_in[2]; // [3][256][256]
    const float* a_l   = (const float*)d_in[3]; // [3][8][32]
    const float* a_r   = (const float*)d_in[4];
    const float* bias  = (const float*)d_in[5]; // [3][256]
    const float* att_w = (const float*)d_in[6]; // [256]
    const float* att_b = (const float*)d_in[7]; // [1]
    float* out = (float*)d_out;

    // Workspace (~142 MB). part (19.2 MB) aliases ot0 (25.6 MB): consumed by
    // p2_csr before gat_gather(t=0) writes ot0 (single stream, sequential).
    char* w = (char*)d_ws;
    unsigned short* xb = (unsigned short*)w; w += (size_t)N_NODES * W_IN * 2;   // 25.6 MB
    unsigned short* H  = (unsigned short*)w; w += (size_t)N_NODES * W_OUT * 2;  // 25.6 MB
    unsigned short* Wt = (unsigned short*)w; w += (size_t)NUM_T * 65536 * 2;    // 0.39 MB
    unsigned short* ot0 = (unsigned short*)w; w += (size_t)N_NODES * W_OUT * 2; // 25.6 MB
    unsigned short* ot1 = (unsigned short*)w; w += (size_t)N_NODES * W_OUT * 2; // 25.6 MB
    unsigned short* ot2 = (unsigned short*)w; w += (size_t)N_NODES * W_OUT * 2; // 25.6 MB
    float* el  = (float*)w; w += (size_t)N_NODES * HEADS * 4;   // 1.6 MB
    float* er  = (float*)w; w += (size_t)N_NODES * HEADS * 4;   // 1.6 MB
    int* csr_src = (int*)w; w += (size_t)NUM_T * N_EDGES * 4;   // 9.6 MB
    int* row_ptr = (int*)w; w += (size_t)NUM_T * (N_NODES + 1) * 4;
    int* bucket_cnt = (int*)w; w += NUM_T * NB * 4;
    int* bucket_ptr = (int*)w; w += NUM_T * (NB + 1) * 4;
    int* bucket_cur = (int*)w; w += NUM_T * NB * 4;
    uint2* part = (uint2*)ot0;   // 19.2 MB alias

    unsigned short* ot[NUM_T] = {ot0, ot1, ot2};
    const int node_wave_blocks = (N_NODES + 3) / 4;  // 12500
    const int gemm_blocks = (N_NODES + 63) / 64;     // 782

    // --- setup: converts + two-level CSR build (all types at once) ---
    hipMemsetAsync(bucket_cnt, 0, NUM_T * NB * sizeof(int), stream);
    convert_x<<<12500, 256, 0, stream>>>(x, xb);
    convert_W<<<dim3(256, NUM_T), 256, 0, stream>>>(Ws, Wt);
    p1_hist<<<dim3(P1_BLOCKS, NUM_T), 256, 0, stream>>>(adj, bucket_cnt);
    p1_scan<<<1, 128, 0, stream>>>(bucket_cnt, bucket_ptr, bucket_cur);
    p1_scatter<<<dim3(P1_BLOCKS, NUM_T), 256, 0, stream>>>(adj, bucket_cur, part);
    p2_csr<<<dim3(NB_USED, NUM_T), 256, 0, stream>>>(part, bucket_ptr, row_ptr,
                                                     csr_src);

    // --- per edge type: fused GEMM+scores -> gather ---
    for (int t = 0; t < NUM_T; ++t) {
        gemm_fused<<<gemm_blocks, 256, 0, stream>>>(
            xb, Wt + (size_t)t * 65536, a_l + t * 256, a_r + t * 256, H, el, er);
        gat_gather<<<node_wave_blocks, 256, 0, stream>>>(
            csr_src + (size_t)t * N_EDGES, row_ptr + (size_t)t * (N_NODES + 1),
            el, er, H, ot[t]);
    }

    combine<<<node_wave_blocks, 256, 0, stream>>>(ot0, ot1, ot2, bias, att_w,
                                                  att_b, out);
}

// Round 6
// 504.216 us; speedup vs baseline: 18.6698x; 1.0379x over previous
//
#include <hip/hip_runtime.h>

#define N_NODES 50000
#define W_IN    256
#define W_OUT   256
#define HEADS   8
#define NUM_T   3
#define N_EDGES 800000
#define NEG_SLOPE 0.2f

#define NB      128           // coarse buckets (98 used)
#define BSH     9             // bucket = dst >> 9  (512 nodes/bucket)
#define BNODES  512
#define P1_EPT  16            // edges per thread in partition kernels
#define P1_CHUNK (256 * P1_EPT)   // 4096 edges per block
#define P1_BLOCKS ((N_EDGES + P1_CHUNK - 1) / P1_CHUNK)  // 196
#define NB_USED ((N_NODES + BNODES - 1) / BNODES)        // 98

typedef __attribute__((ext_vector_type(8))) short bf16x8;
typedef __attribute__((ext_vector_type(4))) float f32x4;

__device__ __forceinline__ unsigned short f2b(float f) {
    unsigned u = __float_as_uint(f);
    u = (u + 0x7fffu + ((u >> 16) & 1u)) >> 16;
    return (unsigned short)u;
}
__device__ __forceinline__ float blo(unsigned u) { return __uint_as_float(u << 16); }
__device__ __forceinline__ float bhi(unsigned u) { return __uint_as_float(u & 0xffff0000u); }

// ---------------------------------------------------------------------------
// x fp32 -> bf16 (RNE). 12500 blocks * 256 threads * 4 elems = 12.8M exact.
// ---------------------------------------------------------------------------
__global__ __launch_bounds__(256) void convert_x(const float* __restrict__ x,
                                                 unsigned short* __restrict__ xb) {
    const size_t i = ((size_t)blockIdx.x * 256 + threadIdx.x) * 4;
    const float4 v = *(const float4*)(x + i);
    ushort4 o;
    o.x = f2b(v.x); o.y = f2b(v.y); o.z = f2b(v.z); o.w = f2b(v.w);
    *(ushort4*)(xb + i) = o;
}

// ---------------------------------------------------------------------------
// W fp32 [t][k][n] -> bf16 transposed [t][n][k].
// ---------------------------------------------------------------------------
__global__ __launch_bounds__(256) void convert_W(const float* __restrict__ Wsrc,
                                                 unsigned short* __restrict__ Wt) {
    const int t = blockIdx.y;
    const int gid = blockIdx.x * 256 + threadIdx.x;  // 0..65535
    const int k = gid >> 8, n = gid & 255;
    Wt[(size_t)t * 65536 + (size_t)n * 256 + k] = f2b(Wsrc[(size_t)t * 65536 + gid]);
}

// ---------------------------------------------------------------------------
// Partition level 1a: coarse histogram (LDS-aggregated).
// ---------------------------------------------------------------------------
__global__ __launch_bounds__(256) void p1_hist(const int* __restrict__ adj,
                                               int* __restrict__ bucket_cnt) {
    __shared__ int lh[NB];
    const int t = blockIdx.y;
    const int tid = threadIdx.x;
    if (tid < NB) lh[tid] = 0;
    __syncthreads();

    const int* dstp = adj + (size_t)t * 2 * N_EDGES + N_EDGES;
    const int e0 = blockIdx.x * P1_CHUNK + tid * P1_EPT;
#pragma unroll
    for (int i = 0; i < P1_EPT; ++i) {
        const int e = e0 + i;
        if (e < N_EDGES) atomicAdd(&lh[dstp[e] >> BSH], 1);
    }
    __syncthreads();
    if (tid < NB && lh[tid] > 0) atomicAdd(&bucket_cnt[t * NB + tid], lh[tid]);
}

// ---------------------------------------------------------------------------
// Partition level 1b: scan 128 bucket counts per type. One block, 128 thr.
// ---------------------------------------------------------------------------
__global__ __launch_bounds__(128) void p1_scan(const int* __restrict__ bucket_cnt,
                                               int* __restrict__ bucket_ptr,
                                               int* __restrict__ bucket_cur) {
    __shared__ int s[NB];
    const int tid = threadIdx.x;
    for (int t = 0; t < NUM_T; ++t) {
        const int v = bucket_cnt[t * NB + tid];
        s[tid] = v;
        __syncthreads();
        for (int off = 1; off < NB; off <<= 1) {
            int o = (tid >= off) ? s[tid - off] : 0;
            __syncthreads();
            s[tid] += o;
            __syncthreads();
        }
        const int incl = s[tid];
        const int excl = incl - v;
        bucket_ptr[t * (NB + 1) + tid] = excl;
        bucket_cur[t * NB + tid] = excl;
        if (tid == NB - 1) bucket_ptr[t * (NB + 1) + NB] = incl;
        __syncthreads();
    }
}

// ---------------------------------------------------------------------------
// Partition level 1c v2: LDS counting-sort, then contiguous flush.
// Edges are ranked per-bucket in LDS, staged reordered in a 32 KB LDS buffer,
// and flushed as contiguous per-bucket runs into the global windows -> writes
// are bursty/coalesced instead of 8 B random (round-5 write-churn fix).
// ---------------------------------------------------------------------------
__global__ __launch_bounds__(256) void p1_scatter(const int* __restrict__ adj,
                                                  int* __restrict__ bucket_cur,
                                                  uint2* __restrict__ part) {
    __shared__ int lh[NB];
    __shared__ int loff[NB];
    __shared__ int lbase[NB];
    __shared__ uint2 buf[P1_CHUNK];   // 32 KB
    const int t = blockIdx.y;
    const int tid = threadIdx.x;
    const int lane = tid & 63;
    const int wave = tid >> 6;
    if (tid < NB) lh[tid] = 0;
    __syncthreads();

    const int* srcp = adj + (size_t)t * 2 * N_EDGES;
    const int* dstp = srcp + N_EDGES;
    const int e0 = blockIdx.x * P1_CHUNK + tid * P1_EPT;

    int es[P1_EPT], ed[P1_EPT], rk[P1_EPT];
#pragma unroll
    for (int i = 0; i < P1_EPT; ++i) {
        const int e = e0 + i;
        if (e < N_EDGES) {
            es[i] = srcp[e];
            ed[i] = dstp[e];
            rk[i] = atomicAdd(&lh[ed[i] >> BSH], 1);
        } else {
            ed[i] = -1;
        }
    }
    __syncthreads();

    // global window reserve (one atomic per non-empty bucket)
    if (tid < NB && lh[tid] > 0)
        lbase[tid] = atomicAdd(&bucket_cur[t * NB + tid], lh[tid]);
    // local exclusive scan of lh -> loff (wave 0, 2 buckets/lane)
    if (wave == 0) {
        const int c0 = lh[lane * 2], c1 = lh[lane * 2 + 1];
        const int s = c0 + c1;
        int run = s;
        for (int off = 1; off < 64; off <<= 1) {
            const int o = __shfl_up(run, off);
            if (lane >= off) run += o;
        }
        const int base = run - s;
        loff[lane * 2] = base;
        loff[lane * 2 + 1] = base + c0;
    }
    __syncthreads();

#pragma unroll
    for (int i = 0; i < P1_EPT; ++i)
        if (ed[i] >= 0)
            buf[loff[ed[i] >> BSH] + rk[i]] =
                make_uint2((unsigned)es[i], (unsigned)ed[i]);
    __syncthreads();

    uint2* pt = part + (size_t)t * N_EDGES;
    int nvalid = N_EDGES - blockIdx.x * P1_CHUNK;
    if (nvalid > P1_CHUNK) nvalid = P1_CHUNK;
    for (int idx = tid; idx < nvalid; idx += 256) {
        const uint2 e = buf[idx];
        const int b = (int)(e.y >> BSH);
        pt[lbase[b] + (idx - loff[b])] = e;
    }
}

// ---------------------------------------------------------------------------
// Partition level 2: per-bucket local CSR. One block per (bucket, type).
// ---------------------------------------------------------------------------
__global__ __launch_bounds__(256) void p2_csr(const uint2* __restrict__ part,
                                              const int* __restrict__ bucket_ptr,
                                              int* __restrict__ row_ptr_all,
                                              int* __restrict__ csr_all) {
    __shared__ int sc[BNODES];
    const int b = blockIdx.x;
    const int t = blockIdx.y;
    const int tid = threadIdx.x;
    const int lane = tid & 63;
    const int wave = tid >> 6;

    const uint2* pt = part + (size_t)t * N_EDGES;
    int* row_ptr = row_ptr_all + (size_t)t * (N_NODES + 1);
    int* csr = csr_all + (size_t)t * N_EDGES;

    const int bp0 = bucket_ptr[t * (NB + 1) + b];
    const int bp1 = bucket_ptr[t * (NB + 1) + b + 1];
    const int node0 = b * BNODES;
    int nn = N_NODES - node0; if (nn > BNODES) nn = BNODES;

    sc[tid] = 0; sc[tid + 256] = 0;
    __syncthreads();

    for (int idx = bp0 + tid; idx < bp1; idx += 256)
        atomicAdd(&sc[pt[idx].y - node0], 1);
    __syncthreads();

    if (wave == 0) {
        int v[8], ex[8];
        int s = 0;
#pragma unroll
        for (int i = 0; i < 8; ++i) { v[i] = sc[lane * 8 + i]; ex[i] = s; s += v[i]; }
        int run = s;
        for (int off = 1; off < 64; off <<= 1) {
            int o = __shfl_up(run, off);
            if (lane >= off) run += o;
        }
        const int base = run - s;
#pragma unroll
        for (int i = 0; i < 8; ++i) sc[lane * 8 + i] = base + ex[i];
    }
    __syncthreads();

    for (int i = tid; i < nn; i += 256) row_ptr[node0 + i] = bp0 + sc[i];
    if (b == NB_USED - 1 && tid == 0) row_ptr[N_NODES] = N_EDGES;
    __syncthreads();

    for (int idx = bp0 + tid; idx < bp1; idx += 256) {
        const uint2 e = pt[idx];
        const int pos = bp0 + atomicAdd(&sc[e.y - node0], 1);
        csr[pos] = (int)e.x;
    }
}

// ---------------------------------------------------------------------------
// GEMM + fused attention scores (unchanged from round 5).
// ---------------------------------------------------------------------------
__global__ __launch_bounds__(256) void gemm_fused(const unsigned short* __restrict__ xb,
                                                  const unsigned short* __restrict__ Wt,
                                                  const float* __restrict__ al,
                                                  const float* __restrict__ ar,
                                                  unsigned short* __restrict__ H,
                                                  float* __restrict__ el,
                                                  float* __restrict__ er) {
    __shared__ unsigned short As[64 * 40];
    __shared__ unsigned short Bs[256 * 40];
    __shared__ float els[64 * 8];
    __shared__ float ers[64 * 8];

    const int tid = threadIdx.x;
    const int wave = tid >> 6;
    const int lane = tid & 63;
    const int quad = lane >> 4;
    const int l16 = lane & 15;
    const int m0 = blockIdx.x * 64;

    f32x4 acc[4][4] = {};

    const int arow = tid >> 2;
    const int achunk = (tid & 3) * 8;
    int gm = m0 + arow;
    if (gm > N_NODES - 1) gm = N_NODES - 1;
    const unsigned short* aptr = xb + (size_t)gm * W_IN + achunk;

    for (int k0 = 0; k0 < W_IN; k0 += 32) {
        const uint4 av = *(const uint4*)(aptr + k0);
        *(uint4*)&As[arow * 40 + achunk] = av;
#pragma unroll
        for (int i = 0; i < 4; ++i) {
            const int idx = i * 256 + tid;
            const int brow = idx >> 2;
            const int bch = (idx & 3) * 8;
            const uint4 bv = *(const uint4*)(Wt + (size_t)brow * W_IN + k0 + bch);
            *(uint4*)&Bs[brow * 40 + bch] = bv;
        }
        __syncthreads();

        bf16x8 af[4], bfr[4];
#pragma unroll
        for (int mi = 0; mi < 4; ++mi)
            af[mi] = *(const bf16x8*)&As[(mi * 16 + l16) * 40 + quad * 8];
#pragma unroll
        for (int ni = 0; ni < 4; ++ni)
            bfr[ni] = *(const bf16x8*)&Bs[(wave * 64 + ni * 16 + l16) * 40 + quad * 8];
#pragma unroll
        for (int mi = 0; mi < 4; ++mi)
#pragma unroll
            for (int ni = 0; ni < 4; ++ni)
                acc[mi][ni] = __builtin_amdgcn_mfma_f32_16x16x32_bf16(
                    af[mi], bfr[ni], acc[mi][ni], 0, 0, 0);
        __syncthreads();
    }

#pragma unroll
    for (int mi = 0; mi < 4; ++mi)
#pragma unroll
        for (int reg = 0; reg < 4; ++reg) {
            const int gr = m0 + mi * 16 + quad * 4 + reg;
            if (gr < N_NODES)
#pragma unroll
                for (int ni = 0; ni < 4; ++ni)
                    H[(size_t)gr * W_OUT + wave * 64 + ni * 16 + l16] =
                        f2b(acc[mi][ni][reg]);
        }

    float al4[4], ar4[4];
#pragma unroll
    for (int ni = 0; ni < 4; ++ni) {
        const int c = wave * 64 + ni * 16 + l16;
        al4[ni] = al[c];
        ar4[ni] = ar[c];
    }
#pragma unroll
    for (int mi = 0; mi < 4; ++mi) {
        float pl[4][2] = {}, pr[4][2] = {};
#pragma unroll
        for (int ni = 0; ni < 4; ++ni) {
            const int hl = ni >> 1;
#pragma unroll
            for (int reg = 0; reg < 4; ++reg) {
                pl[reg][hl] += acc[mi][ni][reg] * al4[ni];
                pr[reg][hl] += acc[mi][ni][reg] * ar4[ni];
            }
        }
#pragma unroll
        for (int off = 1; off < 16; off <<= 1)
#pragma unroll
            for (int reg = 0; reg < 4; ++reg)
#pragma unroll
                for (int hl = 0; hl < 2; ++hl) {
                    pl[reg][hl] += __shfl_xor(pl[reg][hl], off);
                    pr[reg][hl] += __shfl_xor(pr[reg][hl], off);
                }
        if (l16 == 0)
#pragma unroll
            for (int reg = 0; reg < 4; ++reg)
#pragma unroll
                for (int hl = 0; hl < 2; ++hl) {
                    const int row = mi * 16 + quad * 4 + reg;
                    els[row * 8 + wave * 2 + hl] = pl[reg][hl];
                    ers[row * 8 + wave * 2 + hl] = pr[reg][hl];
                }
    }
    __syncthreads();

    int nn = N_NODES - m0; if (nn > 64) nn = 64;
    const int nn8 = nn * 8;
    const int i = tid * 4;
    if (i < nn8) {
        *(float4*)(el + (size_t)m0 * 8 + i) = *(float4*)&els[i];
        *(float4*)(er + (size_t)m0 * 8 + i) = *(float4*)&ers[i];
    }
}

// ---------------------------------------------------------------------------
// Gather v3: 2 edges per wave-instruction + 1-deep software pipeline.
// lane = half*32 + d8; pair q covers edges 2q, 2q+1. The (src, H-row, el)
// for pair q+1 is issued BEFORE processing pair q, so the vmcnt wait covers
// the previous iteration's compute (latency hiding, G7).
// ---------------------------------------------------------------------------
__global__ __launch_bounds__(256) void gat_gather(const int* __restrict__ csr_src,
                                                  const int* __restrict__ row_ptr,
                                                  const float* __restrict__ el,
                                                  const float* __restrict__ er,
                                                  const unsigned short* __restrict__ H,
                                                  unsigned short* __restrict__ ot) {
    const int node = (blockIdx.x * blockDim.x + threadIdx.x) >> 6;
    const int lane = threadIdx.x & 63;
    if (node >= N_NODES) return;
    const int half = lane >> 5;
    const int d8 = lane & 31;
    const int hh = d8 >> 2;

    const int beg = row_ptr[node];
    const int deg = row_ptr[node + 1] - beg;
    const float erv = er[(size_t)node * HEADS + hh];

    float2 acc[4] = {};
    float ssum = 0.f;

    if (deg > 0) {
        int mysrc = (lane < deg) ? csr_src[beg + lane] : 0;
        const int npairs = (deg + 1) >> 1;

        // prologue: load pair 0 (edge ei = half)
        int src0 = __shfl(mysrc, half);
        uint4 u0 = *(const uint4*)(H + (size_t)src0 * W_OUT + d8 * 8);
        float elv0 = el[(size_t)src0 * HEADS + hh];

        for (int q = 0; q < npairs; ++q) {
            int src1 = 0; uint4 u1 = u0; float elv1 = 0.f;
            const int q1 = q + 1;
            if (q1 < npairs) {
                if ((q1 & 31) == 0) {
                    const int cb = beg + (q1 >> 5) * 64;
                    mysrc = (cb + lane < beg + deg) ? csr_src[cb + lane] : 0;
                }
                src1 = __shfl(mysrc, (2 * q1 + half) & 63);
                u1 = *(const uint4*)(H + (size_t)src1 * W_OUT + d8 * 8);
                elv1 = el[(size_t)src1 * HEADS + hh];
            }
            float v = elv0 + erv;
            v = (v > 0.f) ? v : NEG_SLOPE * v;
            const float w = (2 * q + half < deg) ? __expf(v) : 0.f;
            acc[0].x += w * blo(u0.x); acc[0].y += w * bhi(u0.x);
            acc[1].x += w * blo(u0.y); acc[1].y += w * bhi(u0.y);
            acc[2].x += w * blo(u0.z); acc[2].y += w * bhi(u0.z);
            acc[3].x += w * blo(u0.w); acc[3].y += w * bhi(u0.w);
            ssum += w;
            src0 = src1; u0 = u1; elv0 = elv1;
        }
    }

#pragma unroll
    for (int i = 0; i < 4; ++i) {
        acc[i].x += __shfl_xor(acc[i].x, 32);
        acc[i].y += __shfl_xor(acc[i].y, 32);
    }
    ssum += __shfl_xor(ssum, 32);

    if (half == 0) {
        const float inv = 1.f / (ssum + 1e-9f);
        unsigned short o8[8];
#pragma unroll
        for (int i = 0; i < 4; ++i) {
            o8[2 * i]     = f2b(acc[i].x * inv);
            o8[2 * i + 1] = f2b(acc[i].y * inv);
        }
        *(uint4*)(ot + (size_t)node * W_OUT + d8 * 8) = *(const uint4*)o8;
    }
}

// ---------------------------------------------------------------------------
// Semantic attention combine: bf16 ot inputs, fp32 out.
// ---------------------------------------------------------------------------
__global__ __launch_bounds__(256) void combine(const unsigned short* __restrict__ ot0,
                                               const unsigned short* __restrict__ ot1,
                                               const unsigned short* __restrict__ ot2,
                                               const float* __restrict__ bias,
                                               const float* __restrict__ att_w,
                                               const float* __restrict__ att_b,
                                               float* __restrict__ out) {
    const int gw = (blockIdx.x * blockDim.x + threadIdx.x) >> 6;
    const int lane = threadIdx.x & 63;
    if (gw >= N_NODES) return;

    const float4 aw = *(const float4*)(att_w + lane * 4);
    const size_t base = (size_t)gw * W_OUT + lane * 4;

    float4 v[NUM_T];
    float p[NUM_T];
    const unsigned short* ots[NUM_T] = {ot0, ot1, ot2};
#pragma unroll
    for (int t = 0; t < NUM_T; ++t) {
        const uint2 u = *(const uint2*)(ots[t] + base);
        const float4 bv = *(const float4*)(bias + t * W_OUT + lane * 4);
        float4 hv;
        hv.x = blo(u.x) + bv.x;
        hv.y = bhi(u.x) + bv.y;
        hv.z = blo(u.y) + bv.z;
        hv.w = bhi(u.y) + bv.w;
        v[t] = hv;
        p[t] = hv.x * aw.x + hv.y * aw.y + hv.z * aw.z + hv.w * aw.w;
    }
#pragma unroll
    for (int off = 1; off < 64; off <<= 1) {
        p[0] += __shfl_xor(p[0], off);
        p[1] += __shfl_xor(p[1], off);
        p[2] += __shfl_xor(p[2], off);
    }
    const float ab = att_b[0];
    const float a0 = p[0] + ab, a1 = p[1] + ab, a2 = p[2] + ab;
    float4 o;
    o.x = a0 * v[0].x + a1 * v[1].x + a2 * v[2].x;
    o.y = a0 * v[0].y + a1 * v[1].y + a2 * v[2].y;
    o.z = a0 * v[0].z + a1 * v[1].z + a2 * v[2].z;
    o.w = a0 * v[0].w + a1 * v[1].w + a2 * v[2].w;
    *(float4*)(out + base) = o;
}

// ---------------------------------------------------------------------------
extern "C" void kernel_launch(void* const* d_in, const int* in_sizes, int n_in,
                              void* d_out, int out_size, void* d_ws, size_t ws_size,
                              hipStream_t stream) {
    const float* x     = (const float*)d_in[0];
    const int*   adj   = (const int*)d_in[1];   // [3][2][N_EDGES]
    const float* Ws    = (const float*)d_in[2]; // [3][256][256]
    const float* a_l   = (const float*)d_in[3]; // [3][8][32]
    const float* a_r   = (const float*)d_in[4];
    const float* bias  = (const float*)d_in[5]; // [3][256]
    const float* att_w = (const float*)d_in[6]; // [256]
    const float* att_b = (const float*)d_in[7]; // [1]
    float* out = (float*)d_out;

    // Workspace (~142 MB). part (19.2 MB) aliases ot0 (25.6 MB): consumed by
    // p2_csr before gat_gather(t=0) writes ot0 (single stream, sequential).
    char* w = (char*)d_ws;
    unsigned short* xb = (unsigned short*)w; w += (size_t)N_NODES * W_IN * 2;   // 25.6 MB
    unsigned short* H  = (unsigned short*)w; w += (size_t)N_NODES * W_OUT * 2;  // 25.6 MB
    unsigned short* Wt = (unsigned short*)w; w += (size_t)NUM_T * 65536 * 2;    // 0.39 MB
    unsigned short* ot0 = (unsigned short*)w; w += (size_t)N_NODES * W_OUT * 2; // 25.6 MB
    unsigned short* ot1 = (unsigned short*)w; w += (size_t)N_NODES * W_OUT * 2; // 25.6 MB
    unsigned short* ot2 = (unsigned short*)w; w += (size_t)N_NODES * W_OUT * 2; // 25.6 MB
    float* el  = (float*)w; w += (size_t)N_NODES * HEADS * 4;   // 1.6 MB
    float* er  = (float*)w; w += (size_t)N_NODES * HEADS * 4;   // 1.6 MB
    int* csr_src = (int*)w; w += (size_t)NUM_T * N_EDGES * 4;   // 9.6 MB
    int* row_ptr = (int*)w; w += (size_t)NUM_T * (N_NODES + 1) * 4;
    int* bucket_cnt = (int*)w; w += NUM_T * NB * 4;
    int* bucket_ptr = (int*)w; w += NUM_T * (NB + 1) * 4;
    int* bucket_cur = (int*)w; w += NUM_T * NB * 4;
    uint2* part = (uint2*)ot0;   // 19.2 MB alias

    unsigned short* ot[NUM_T] = {ot0, ot1, ot2};
    const int node_wave_blocks = (N_NODES + 3) / 4;  // 12500
    const int gemm_blocks = (N_NODES + 63) / 64;     // 782

    // --- setup: converts + two-level CSR build (all types at once) ---
    hipMemsetAsync(bucket_cnt, 0, NUM_T * NB * sizeof(int), stream);
    convert_x<<<12500, 256, 0, stream>>>(x, xb);
    convert_W<<<dim3(256, NUM_T), 256, 0, stream>>>(Ws, Wt);
    p1_hist<<<dim3(P1_BLOCKS, NUM_T), 256, 0, stream>>>(adj, bucket_cnt);
    p1_scan<<<1, 128, 0, stream>>>(bucket_cnt, bucket_ptr, bucket_cur);
    p1_scatter<<<dim3(P1_BLOCKS, NUM_T), 256, 0, stream>>>(adj, bucket_cur, part);
    p2_csr<<<dim3(NB_USED, NUM_T), 256, 0, stream>>>(part, bucket_ptr, row_ptr,
                                                     csr_src);

    // --- per edge type: fused GEMM+scores -> gather ---
    for (int t = 0; t < NUM_T; ++t) {
        gemm_fused<<<gemm_blocks, 256, 0, stream>>>(
            xb, Wt + (size_t)t * 65536, a_l + t * 256, a_r + t * 256, H, el, er);
        gat_gather<<<node_wave_blocks, 256, 0, stream>>>(
            csr_src + (size_t)t * N_EDGES, row_ptr + (size_t)t * (N_NODES + 1),
            el, er, H, ot[t]);
    }

    combine<<<node_wave_blocks, 256, 0, stream>>>(ot0, ot1, ot2, bias, att_w,
                                                  att_b, out);
}